// Round 1
// baseline (1213.085 us; speedup 1.0000x reference)
//
#include <hip/hip_runtime.h>

#define NN 50000
#define NE 800000
#define NG 64
#define FD 64
#define BN_EPS 1e-5f

// ---------------- degree / norm ----------------
__global__ void k_deg_count(const int* __restrict__ col, float* __restrict__ deg) {
    int e = blockIdx.x * blockDim.x + threadIdx.x;
    if (e < NE) atomicAdd(&deg[col[e]], 1.0f);
}

__global__ void k_dinv(float* __restrict__ deg) {
    int i = blockIdx.x * blockDim.x + threadIdx.x;
    if (i < NN) deg[i] = rsqrtf(deg[i] + 1.0f);  // +1 self-loop; deg>0 always
}

__global__ void k_norm(const int* __restrict__ row, const int* __restrict__ col,
                       const float* __restrict__ dinv, float* __restrict__ norm) {
    int e = blockIdx.x * blockDim.x + threadIdx.x;
    if (e < NE) norm[e] = dinv[row[e]] * dinv[col[e]];
}

// ---------------- layer 1: scalar propagation ----------------
// s = A_hat * x  (x is [N,1]); layer1 output before BN is s[i]*W1[j] + b1[j]
__global__ void k_s_init(const float* __restrict__ x, const float* __restrict__ dinv,
                         float* __restrict__ s) {
    int i = blockIdx.x * blockDim.x + threadIdx.x;
    if (i < NN) { float d = dinv[i]; s[i] = x[i] * d * d; }
}

__global__ void k_s_scatter(const int* __restrict__ row, const int* __restrict__ col,
                            const float* __restrict__ x, const float* __restrict__ norm,
                            float* __restrict__ s) {
    int e = blockIdx.x * blockDim.x + threadIdx.x;
    if (e < NE) atomicAdd(&s[col[e]], x[row[e]] * norm[e]);
}

__global__ __launch_bounds__(256) void k_scalar_stats(const float* __restrict__ s,
                                                      float* __restrict__ stats) {
    __shared__ float ls[256], lq[256];
    float a = 0.f, b = 0.f;
    for (int i = blockIdx.x * blockDim.x + threadIdx.x; i < NN; i += gridDim.x * blockDim.x) {
        float v = s[i]; a += v; b += v * v;
    }
    ls[threadIdx.x] = a; lq[threadIdx.x] = b; __syncthreads();
    for (int st = 128; st > 0; st >>= 1) {
        if (threadIdx.x < st) { ls[threadIdx.x] += ls[threadIdx.x + st]; lq[threadIdx.x] += lq[threadIdx.x + st]; }
        __syncthreads();
    }
    if (threadIdx.x == 0) { atomicAdd(&stats[0], ls[0]); atomicAdd(&stats[1], lq[0]); }
}

// y1[i][j] = relu(alpha[j]*s[i] + c[j]); BN of (s*w+b1) folds to alpha = g*w*rsqrt(var_s*w^2+eps)
__global__ void k_l1_coeffs(const float* __restrict__ stats, const float* __restrict__ W1,
                            const float* __restrict__ b1, const float* __restrict__ g1,
                            const float* __restrict__ bt1,
                            float* __restrict__ alpha, float* __restrict__ cshift) {
    int j = threadIdx.x;
    if (j < FD) {
        float mean = stats[0] * (1.0f / NN);
        float var  = stats[1] * (1.0f / NN) - mean * mean;
        float w = W1[j];
        float rinv = rsqrtf(var * w * w + BN_EPS);
        float a = g1[j] * w * rinv;
        alpha[j]  = a;
        cshift[j] = bt1[j] - a * mean;
    }
}

__global__ void k_l1_apply(const float* __restrict__ s, const float* __restrict__ alpha,
                           const float* __restrict__ cshift, float* __restrict__ xo) {
    int t = blockIdx.x * blockDim.x + threadIdx.x;
    int i = t >> 6, j = t & 63;
    if (i < NN) xo[t] = fmaxf(alpha[j] * s[i] + cshift[j], 0.0f);
}

// ---------------- dense 64x64 matmul ----------------
__global__ __launch_bounds__(256) void k_matmul64(const float* __restrict__ x,
                                                  const float* __restrict__ W,
                                                  float* __restrict__ h) {
    __shared__ float Ws[64 * 64];
    __shared__ float xs[4 * 64];
    int t = threadIdx.x;
    for (int k = t; k < 64 * 64; k += 256) Ws[k] = W[k];
    int n0 = blockIdx.x * 4;
    int j = t & 63, n = t >> 6;
    int node = n0 + n;
    int gidx = n0 * 64 + t;
    xs[t] = (gidx < NN * 64) ? x[gidx] : 0.0f;
    __syncthreads();
    if (node < NN) {
        float acc = 0.f;
        #pragma unroll
        for (int k = 0; k < 64; ++k) acc += xs[n * 64 + k] * Ws[k * 64 + j];
        h[node * 64 + j] = acc;
    }
}

// agg init with self-loop + bias
__global__ void k_agg_init(const float* __restrict__ h, const float* __restrict__ dinv,
                           const float* __restrict__ b, float* __restrict__ agg) {
    int t = blockIdx.x * blockDim.x + threadIdx.x;
    int i = t >> 6, j = t & 63;
    if (i < NN) { float d = dinv[i]; agg[t] = h[t] * d * d + b[j]; }
}

// edge scatter: wave-uniform edge, lane = feature
__global__ __launch_bounds__(256) void k_scatter(const int* __restrict__ row, const int* __restrict__ col,
                                                 const float* __restrict__ norm, const float* __restrict__ h,
                                                 float* __restrict__ agg) {
    int t = blockIdx.x * blockDim.x + threadIdx.x;
    int e = __builtin_amdgcn_readfirstlane(t >> 6);  // uniform per wave64
    int j = threadIdx.x & 63;
    if (e < NE) {
        int r = row[e], c = col[e];
        float nv = norm[e];
        float v = h[r * 64 + j] * nv;
        atomicAdd(&agg[c * 64 + j], v);
    }
}

// ---------------- batchnorm ----------------
__global__ __launch_bounds__(256) void k_bn_stats(const float* __restrict__ agg,
                                                  float* __restrict__ bnsum, float* __restrict__ bnsq) {
    __shared__ float ls[256], lq[256];
    int j = threadIdx.x & 63, nl = threadIdx.x >> 6;
    float a = 0.f, b = 0.f;
    for (int i = blockIdx.x * 4 + nl; i < NN; i += gridDim.x * 4) {
        float v = agg[i * 64 + j]; a += v; b += v * v;
    }
    ls[threadIdx.x] = a; lq[threadIdx.x] = b; __syncthreads();
    if (threadIdx.x < 128) { ls[threadIdx.x] += ls[threadIdx.x + 128]; lq[threadIdx.x] += lq[threadIdx.x + 128]; }
    __syncthreads();
    if (threadIdx.x < 64) {
        atomicAdd(&bnsum[j], ls[threadIdx.x] + ls[threadIdx.x + 64]);
        atomicAdd(&bnsq[j],  lq[threadIdx.x] + lq[threadIdx.x + 64]);
    }
}

__global__ void k_bn_finalize(const float* __restrict__ bnsum, const float* __restrict__ bnsq,
                              const float* __restrict__ g, const float* __restrict__ bt,
                              float* __restrict__ scale, float* __restrict__ shift) {
    int j = threadIdx.x;
    if (j < FD) {
        float mean = bnsum[j] * (1.0f / NN);
        float var  = bnsq[j] * (1.0f / NN) - mean * mean;
        float rinv = rsqrtf(var + BN_EPS);
        float sc = g[j] * rinv;
        scale[j] = sc;
        shift[j] = bt[j] - sc * mean;
    }
}

__global__ void k_bn_apply(const float* __restrict__ agg, const float* __restrict__ scale,
                           const float* __restrict__ shift, float* __restrict__ xo) {
    int t = blockIdx.x * blockDim.x + threadIdx.x;
    int i = t >> 6, j = t & 63;
    if (i < NN) xo[t] = fmaxf(scale[j] * agg[t] + shift[j], 0.0f);
}

// ---------------- pooling + FC ----------------
__global__ void k_pool(const float* __restrict__ x, const int* __restrict__ batch,
                       float* __restrict__ pooled, float* __restrict__ cnt) {
    int t = blockIdx.x * blockDim.x + threadIdx.x;
    int i = t >> 6, j = t & 63;
    if (i < NN) {
        int b = batch[i];
        atomicAdd(&pooled[b * 64 + j], x[t]);
        if (j == 0) atomicAdd(&cnt[b], 1.0f);
    }
}

__global__ __launch_bounds__(128) void k_fc(const float* __restrict__ pooled, const float* __restrict__ cnt,
                                            const float* __restrict__ fw1, const float* __restrict__ fb1,
                                            const float* __restrict__ fw2, const float* __restrict__ fb2,
                                            float* __restrict__ out) {
    __shared__ float p[64], hsh[128];
    int g = blockIdx.x, t = threadIdx.x;
    if (t < 64) {
        float c = cnt[g]; c = c < 1.f ? 1.f : c;
        p[t] = pooled[g * 64 + t] / c;
    }
    __syncthreads();
    float acc = fb1[t];
    #pragma unroll 8
    for (int k = 0; k < 64; ++k) acc += p[k] * fw1[t * 64 + k];
    hsh[t] = fmaxf(acc, 0.f);
    __syncthreads();
    if (t < 10) {
        float o = fb2[t];
        #pragma unroll 8
        for (int k = 0; k < 128; ++k) o += hsh[k] * fw2[t * 128 + k];
        out[g * 10 + t] = o;
    }
}

// ---------------- launch ----------------
extern "C" void kernel_launch(void* const* d_in, const int* in_sizes, int n_in,
                              void* d_out, int out_size, void* d_ws, size_t ws_size,
                              hipStream_t stream) {
    const float* x   = (const float*)d_in[0];
    const int* ei    = (const int*)d_in[1];
    const int* batch = (const int*)d_in[2];
    const float* W[5]  = {nullptr, (const float*)d_in[3],  (const float*)d_in[7],
                                   (const float*)d_in[11], (const float*)d_in[15]};
    const float* bb[5] = {nullptr, (const float*)d_in[4],  (const float*)d_in[8],
                                   (const float*)d_in[12], (const float*)d_in[16]};
    const float* gg[5] = {nullptr, (const float*)d_in[5],  (const float*)d_in[9],
                                   (const float*)d_in[13], (const float*)d_in[17]};
    const float* bt[5] = {nullptr, (const float*)d_in[6],  (const float*)d_in[10],
                                   (const float*)d_in[14], (const float*)d_in[18]};
    const float* fw1 = (const float*)d_in[19];
    const float* fb1 = (const float*)d_in[20];
    const float* fw2 = (const float*)d_in[21];
    const float* fb2 = (const float*)d_in[22];
    float* out = (float*)d_out;

    const int* row = ei;        // edge_index[0]
    const int* col = ei + NE;   // edge_index[1]

    float* ws = (float*)d_ws;
    float* dinv   = ws + 0;          // N
    float* norm   = ws + 50000;      // E
    float* s      = ws + 850000;     // N
    float* stats  = ws + 900000;     // [0]=sum,[1]=sumsq
    float* bnsum  = ws + 900064;     // 64
    float* bnsq   = ws + 900128;     // 64
    float* scale  = ws + 900192;     // 64 (also alpha)
    float* shift  = ws + 900256;     // 64 (also cshift)
    float* pooled = ws + 900352;     // 64*64
    float* cnt    = ws + 904448;     // 64
    float* xbuf   = ws + 1000000;    // N*64
    float* hbuf   = ws + 4200000;    // N*64
    float* aggbuf = ws + 7400000;    // N*64

    const int B = 256;
    int gE  = (NE + B - 1) / B;
    int gN  = (NN + B - 1) / B;
    int gNF = (NN * 64 + B - 1) / B;
    int gEF = (NE * 64 + B - 1) / B;

    // degree + norm
    hipMemsetAsync(dinv, 0, NN * sizeof(float), stream);
    k_deg_count<<<gE, B, 0, stream>>>(col, dinv);
    k_dinv<<<gN, B, 0, stream>>>(dinv);
    k_norm<<<gE, B, 0, stream>>>(row, col, dinv, norm);

    // layer 1 (scalar propagation + folded BN)
    k_s_init<<<gN, B, 0, stream>>>(x, dinv, s);
    k_s_scatter<<<gE, B, 0, stream>>>(row, col, x, norm, s);
    hipMemsetAsync(stats, 0, 2 * sizeof(float), stream);
    k_scalar_stats<<<256, B, 0, stream>>>(s, stats);
    k_l1_coeffs<<<1, 64, 0, stream>>>(stats, W[1], bb[1], gg[1], bt[1], scale, shift);
    k_l1_apply<<<gNF, B, 0, stream>>>(s, scale, shift, xbuf);

    // layers 2..4
    for (int L = 2; L <= 4; ++L) {
        k_matmul64<<<(NN + 3) / 4, B, 0, stream>>>(xbuf, W[L], hbuf);
        k_agg_init<<<gNF, B, 0, stream>>>(hbuf, dinv, bb[L], aggbuf);
        k_scatter<<<gEF, B, 0, stream>>>(row, col, norm, hbuf, aggbuf);
        hipMemsetAsync(bnsum, 0, 128 * sizeof(float), stream);
        k_bn_stats<<<512, B, 0, stream>>>(aggbuf, bnsum, bnsq);
        k_bn_finalize<<<1, 64, 0, stream>>>(bnsum, bnsq, gg[L], bt[L], scale, shift);
        k_bn_apply<<<gNF, B, 0, stream>>>(aggbuf, scale, shift, xbuf);
    }

    // pool + FC
    hipMemsetAsync(pooled, 0, (64 * 64 + 64) * sizeof(float), stream);
    k_pool<<<gNF, B, 0, stream>>>(xbuf, batch, pooled, cnt);
    k_fc<<<NG, 128, 0, stream>>>(pooled, cnt, fw1, fb1, fw2, fb2, out);
}

// Round 2
// 851.676 us; speedup vs baseline: 1.4243x; 1.4243x over previous
//
#include <hip/hip_runtime.h>

#define NN 50000
#define NE 800000
#define NG 64
#define FD 64
#define BN_EPS 1e-5f

// ---------------- degree / norm ----------------
__global__ void k_deg_count(const int* __restrict__ col, float* __restrict__ deg) {
    int e = blockIdx.x * blockDim.x + threadIdx.x;
    if (e < NE) atomicAdd(&deg[col[e]], 1.0f);
}

__global__ void k_dinv(float* __restrict__ deg) {
    int i = blockIdx.x * blockDim.x + threadIdx.x;
    if (i < NN) deg[i] = rsqrtf(deg[i] + 1.0f);  // +1 self-loop; deg>0 always
}

__global__ void k_norm(const int* __restrict__ row, const int* __restrict__ col,
                       const float* __restrict__ dinv, float* __restrict__ norm) {
    int e = blockIdx.x * blockDim.x + threadIdx.x;
    if (e < NE) norm[e] = dinv[row[e]] * dinv[col[e]];
}

// ---------------- layer 1: scalar propagation ----------------
__global__ void k_s_init(const float* __restrict__ x, const float* __restrict__ dinv,
                         float* __restrict__ s) {
    int i = blockIdx.x * blockDim.x + threadIdx.x;
    if (i < NN) { float d = dinv[i]; s[i] = x[i] * d * d; }
}

__global__ void k_s_scatter(const int* __restrict__ row, const int* __restrict__ col,
                            const float* __restrict__ x, const float* __restrict__ norm,
                            float* __restrict__ s) {
    int e = blockIdx.x * blockDim.x + threadIdx.x;
    if (e < NE) atomicAdd(&s[col[e]], x[row[e]] * norm[e]);
}

__global__ __launch_bounds__(256) void k_scalar_stats(const float* __restrict__ s,
                                                      float* __restrict__ stats) {
    __shared__ float ls[256], lq[256];
    float a = 0.f, b = 0.f;
    for (int i = blockIdx.x * blockDim.x + threadIdx.x; i < NN; i += gridDim.x * blockDim.x) {
        float v = s[i]; a += v; b += v * v;
    }
    ls[threadIdx.x] = a; lq[threadIdx.x] = b; __syncthreads();
    for (int st = 128; st > 0; st >>= 1) {
        if (threadIdx.x < st) { ls[threadIdx.x] += ls[threadIdx.x + st]; lq[threadIdx.x] += lq[threadIdx.x + st]; }
        __syncthreads();
    }
    if (threadIdx.x == 0) { atomicAdd(&stats[0], ls[0]); atomicAdd(&stats[1], lq[0]); }
}

__global__ void k_l1_coeffs(const float* __restrict__ stats, const float* __restrict__ W1,
                            const float* __restrict__ b1, const float* __restrict__ g1,
                            const float* __restrict__ bt1,
                            float* __restrict__ alpha, float* __restrict__ cshift) {
    int j = threadIdx.x;
    if (j < FD) {
        float mean = stats[0] * (1.0f / NN);
        float var  = stats[1] * (1.0f / NN) - mean * mean;
        float w = W1[j];
        float rinv = rsqrtf(var * w * w + BN_EPS);
        float a = g1[j] * w * rinv;
        alpha[j]  = a;
        cshift[j] = bt1[j] - a * mean;
    }
}

__global__ void k_l1_apply(const float* __restrict__ s, const float* __restrict__ alpha,
                           const float* __restrict__ cshift, float* __restrict__ xo) {
    int t = blockIdx.x * blockDim.x + threadIdx.x;
    int i = t >> 6, j = t & 63;
    if (i < NN) xo[t] = fmaxf(alpha[j] * s[i] + cshift[j], 0.0f);
}

// ---------------- dense 64x64 matmul ----------------
__global__ __launch_bounds__(256) void k_matmul64(const float* __restrict__ x,
                                                  const float* __restrict__ W,
                                                  float* __restrict__ h) {
    __shared__ float Ws[64 * 64];
    __shared__ float xs[4 * 64];
    int t = threadIdx.x;
    for (int k = t; k < 64 * 64; k += 256) Ws[k] = W[k];
    int n0 = blockIdx.x * 4;
    int j = t & 63, n = t >> 6;
    int node = n0 + n;
    int gidx = n0 * 64 + t;
    xs[t] = (gidx < NN * 64) ? x[gidx] : 0.0f;
    __syncthreads();
    if (node < NN) {
        float acc = 0.f;
        #pragma unroll
        for (int k = 0; k < 64; ++k) acc += xs[n * 64 + k] * Ws[k * 64 + j];
        h[node * 64 + j] = acc;
    }
}

__global__ void k_agg_init(const float* __restrict__ h, const float* __restrict__ dinv,
                           const float* __restrict__ b, float* __restrict__ agg) {
    int t = blockIdx.x * blockDim.x + threadIdx.x;
    int i = t >> 6, j = t & 63;
    if (i < NN) { float d = dinv[i]; agg[t] = h[t] * d * d + b[j]; }
}

__global__ __launch_bounds__(256) void k_scatter(const int* __restrict__ row, const int* __restrict__ col,
                                                 const float* __restrict__ norm, const float* __restrict__ h,
                                                 float* __restrict__ agg) {
    int t = blockIdx.x * blockDim.x + threadIdx.x;
    int e = __builtin_amdgcn_readfirstlane(t >> 6);
    int j = threadIdx.x & 63;
    if (e < NE) {
        int r = row[e], c = col[e];
        float nv = norm[e];
        float v = h[r * 64 + j] * nv;
        atomicAdd(&agg[c * 64 + j], v);
    }
}

// ---------------- batchnorm ----------------
__global__ __launch_bounds__(256) void k_bn_stats(const float* __restrict__ agg,
                                                  float* __restrict__ bnsum, float* __restrict__ bnsq) {
    __shared__ float ls[256], lq[256];
    int j = threadIdx.x & 63, nl = threadIdx.x >> 6;
    float a = 0.f, b = 0.f;
    for (int i = blockIdx.x * 4 + nl; i < NN; i += gridDim.x * 4) {
        float v = agg[i * 64 + j]; a += v; b += v * v;
    }
    ls[threadIdx.x] = a; lq[threadIdx.x] = b; __syncthreads();
    if (threadIdx.x < 128) { ls[threadIdx.x] += ls[threadIdx.x + 128]; lq[threadIdx.x] += lq[threadIdx.x + 128]; }
    __syncthreads();
    if (threadIdx.x < 64) {
        atomicAdd(&bnsum[j], ls[threadIdx.x] + ls[threadIdx.x + 64]);
        atomicAdd(&bnsq[j],  lq[threadIdx.x] + lq[threadIdx.x + 64]);
    }
}

__global__ void k_bn_finalize(const float* __restrict__ bnsum, const float* __restrict__ bnsq,
                              const float* __restrict__ g, const float* __restrict__ bt,
                              float* __restrict__ scale, float* __restrict__ shift) {
    int j = threadIdx.x;
    if (j < FD) {
        float mean = bnsum[j] * (1.0f / NN);
        float var  = bnsq[j] * (1.0f / NN) - mean * mean;
        float rinv = rsqrtf(var + BN_EPS);
        float sc = g[j] * rinv;
        scale[j] = sc;
        shift[j] = bt[j] - sc * mean;
    }
}

__global__ void k_bn_apply(const float* __restrict__ agg, const float* __restrict__ scale,
                           const float* __restrict__ shift, float* __restrict__ xo) {
    int t = blockIdx.x * blockDim.x + threadIdx.x;
    int i = t >> 6, j = t & 63;
    if (i < NN) xo[t] = fmaxf(scale[j] * agg[t] + shift[j], 0.0f);
}

// ---------------- pooling (segmented: batch is sorted) + FC ----------------
__global__ __launch_bounds__(256) void k_pool_seg(const float* __restrict__ x,
                                                  const int* __restrict__ batch,
                                                  float* __restrict__ pooled,
                                                  float* __restrict__ cnt) {
    const int wpb = 4;  // waves per block
    int wave = blockIdx.x * wpb + (threadIdx.x >> 6);
    int lane = threadIdx.x & 63;
    const int nwaves = gridDim.x * wpb;
    int chunk = (NN + nwaves - 1) / nwaves;
    int i0 = wave * chunk;
    int i1 = i0 + chunk; if (i1 > NN) i1 = NN;
    if (i0 >= NN) return;
    float acc = 0.0f;
    int curb = batch[i0];
    int runlen = 0;
    for (int i = i0; i < i1; ++i) {
        int b = batch[i];
        if (b != curb) {
            atomicAdd(&pooled[curb * 64 + lane], acc);
            if (lane == 0) atomicAdd(&cnt[curb], (float)runlen);
            acc = 0.0f; runlen = 0; curb = b;
        }
        acc += x[i * 64 + lane];
        ++runlen;
    }
    atomicAdd(&pooled[curb * 64 + lane], acc);
    if (lane == 0) atomicAdd(&cnt[curb], (float)runlen);
}

__global__ __launch_bounds__(128) void k_fc(const float* __restrict__ pooled, const float* __restrict__ cnt,
                                            const float* __restrict__ fw1, const float* __restrict__ fb1,
                                            const float* __restrict__ fw2, const float* __restrict__ fb2,
                                            float* __restrict__ out) {
    __shared__ float p[64], hsh[128];
    int g = blockIdx.x, t = threadIdx.x;
    if (t < 64) {
        float c = cnt[g]; c = c < 1.f ? 1.f : c;
        p[t] = pooled[g * 64 + t] / c;
    }
    __syncthreads();
    float acc = fb1[t];
    #pragma unroll 8
    for (int k = 0; k < 64; ++k) acc += p[k] * fw1[t * 64 + k];
    hsh[t] = fmaxf(acc, 0.f);
    __syncthreads();
    if (t < 10) {
        float o = fb2[t];
        #pragma unroll 8
        for (int k = 0; k < 128; ++k) o += hsh[k] * fw2[t * 128 + k];
        out[g * 10 + t] = o;
    }
}

// ---------------- launch ----------------
extern "C" void kernel_launch(void* const* d_in, const int* in_sizes, int n_in,
                              void* d_out, int out_size, void* d_ws, size_t ws_size,
                              hipStream_t stream) {
    const float* x   = (const float*)d_in[0];
    const int* ei    = (const int*)d_in[1];
    const int* batch = (const int*)d_in[2];
    const float* W[5]  = {nullptr, (const float*)d_in[3],  (const float*)d_in[7],
                                   (const float*)d_in[11], (const float*)d_in[15]};
    const float* bb[5] = {nullptr, (const float*)d_in[4],  (const float*)d_in[8],
                                   (const float*)d_in[12], (const float*)d_in[16]};
    const float* gg[5] = {nullptr, (const float*)d_in[5],  (const float*)d_in[9],
                                   (const float*)d_in[13], (const float*)d_in[17]};
    const float* bt[5] = {nullptr, (const float*)d_in[6],  (const float*)d_in[10],
                                   (const float*)d_in[14], (const float*)d_in[18]};
    const float* fw1 = (const float*)d_in[19];
    const float* fb1 = (const float*)d_in[20];
    const float* fw2 = (const float*)d_in[21];
    const float* fb2 = (const float*)d_in[22];
    float* out = (float*)d_out;

    const int* row = ei;
    const int* col = ei + NE;

    float* ws = (float*)d_ws;
    float* dinv   = ws + 0;          // N
    float* norm   = ws + 50000;      // E
    float* s      = ws + 850000;     // N
    float* stats  = ws + 900000;
    float* bnsum  = ws + 900064;
    float* bnsq   = ws + 900128;
    float* scale  = ws + 900192;
    float* shift  = ws + 900256;
    float* pooled = ws + 900352;     // 64*64
    float* cnt    = ws + 904448;     // 64
    float* xbuf   = ws + 1000000;    // N*64
    float* hbuf   = ws + 4200000;    // N*64
    float* aggbuf = ws + 7400000;    // N*64

    const int B = 256;
    int gE  = (NE + B - 1) / B;
    int gN  = (NN + B - 1) / B;
    int gNF = (NN * 64 + B - 1) / B;
    int gEF = (NE * 64 + B - 1) / B;

    // degree + norm
    hipMemsetAsync(dinv, 0, NN * sizeof(float), stream);
    k_deg_count<<<gE, B, 0, stream>>>(col, dinv);
    k_dinv<<<gN, B, 0, stream>>>(dinv);
    k_norm<<<gE, B, 0, stream>>>(row, col, dinv, norm);

    // layer 1 (scalar propagation + folded BN)
    k_s_init<<<gN, B, 0, stream>>>(x, dinv, s);
    k_s_scatter<<<gE, B, 0, stream>>>(row, col, x, norm, s);
    hipMemsetAsync(stats, 0, 2 * sizeof(float), stream);
    k_scalar_stats<<<256, B, 0, stream>>>(s, stats);
    k_l1_coeffs<<<1, 64, 0, stream>>>(stats, W[1], bb[1], gg[1], bt[1], scale, shift);
    k_l1_apply<<<gNF, B, 0, stream>>>(s, scale, shift, xbuf);

    // layers 2..4
    for (int L = 2; L <= 4; ++L) {
        k_matmul64<<<(NN + 3) / 4, B, 0, stream>>>(xbuf, W[L], hbuf);
        k_agg_init<<<gNF, B, 0, stream>>>(hbuf, dinv, bb[L], aggbuf);
        k_scatter<<<gEF, B, 0, stream>>>(row, col, norm, hbuf, aggbuf);
        hipMemsetAsync(bnsum, 0, 128 * sizeof(float), stream);
        k_bn_stats<<<512, B, 0, stream>>>(aggbuf, bnsum, bnsq);
        k_bn_finalize<<<1, 64, 0, stream>>>(bnsum, bnsq, gg[L], bt[L], scale, shift);
        k_bn_apply<<<gNF, B, 0, stream>>>(aggbuf, scale, shift, xbuf);
    }

    // pool (segmented) + FC
    hipMemsetAsync(pooled, 0, (64 * 64 + 64) * sizeof(float), stream);
    k_pool_seg<<<512, B, 0, stream>>>(xbuf, batch, pooled, cnt);
    k_fc<<<NG, 128, 0, stream>>>(pooled, cnt, fw1, fb1, fw2, fb2, out);
}

// Round 3
// 528.014 us; speedup vs baseline: 2.2974x; 1.6130x over previous
//
#include <hip/hip_runtime.h>

#define NN 50000
#define NE 800000
#define NG 64
#define FD 64
#define BN_EPS 1e-5f

// ---------------- CSR build ----------------
__global__ void k_hist(const int* __restrict__ col, int* __restrict__ deg) {
    int e = blockIdx.x * blockDim.x + threadIdx.x;
    if (e < NE) atomicAdd(&deg[col[e]], 1);
}

// exclusive prefix sum of deg -> cursor (single block, 1024 threads)
__global__ __launch_bounds__(1024) void k_scan(const int* __restrict__ deg, int* __restrict__ cursor) {
    __shared__ int part[1024];
    const int per = 49;  // 49*1024 >= 50000
    int t = threadIdx.x;
    int i0 = t * per;
    int sum = 0;
    for (int k = 0; k < per; ++k) {
        int i = i0 + k;
        if (i < NN) sum += deg[i];
    }
    part[t] = sum;
    __syncthreads();
    for (int off = 1; off < 1024; off <<= 1) {
        int v = (t >= off) ? part[t - off] : 0;
        __syncthreads();
        part[t] += v;
        __syncthreads();
    }
    int run = (t == 0) ? 0 : part[t - 1];  // exclusive base
    for (int k = 0; k < per; ++k) {
        int i = i0 + k;
        if (i < NN) { cursor[i] = run; run += deg[i]; }
    }
}

// deg(int) -> dinv(float) in place
__global__ void k_dinv(int* __restrict__ degi) {
    int i = blockIdx.x * blockDim.x + threadIdx.x;
    if (i < NN) {
        float d = (float)degi[i];
        ((float*)degi)[i] = rsqrtf(d + 1.0f);
    }
}

// fill eidx; afterwards cursor[i] = inclusive end of bucket i
__global__ void k_fill(const int* __restrict__ row, const int* __restrict__ col,
                       int* __restrict__ cursor, int* __restrict__ eidx) {
    int e = blockIdx.x * blockDim.x + threadIdx.x;
    if (e < NE) {
        int pos = atomicAdd(&cursor[col[e]], 1);
        eidx[pos] = row[e];
    }
}

// ---------------- layer 1: scalar propagation via CSR gather ----------------
__global__ void k_l1_gather(const int* __restrict__ cursor, const int* __restrict__ eidx,
                            const float* __restrict__ dinv, const float* __restrict__ x,
                            float* __restrict__ s) {
    int i = blockIdx.x * blockDim.x + threadIdx.x;
    if (i < NN) {
        int start = i ? cursor[i - 1] : 0;
        int end = cursor[i];
        float acc = 0.0f;
        for (int k = start; k < end; ++k) {
            int r = eidx[k];
            acc += x[r] * dinv[r];
        }
        float di = dinv[i];
        s[i] = di * (acc + di * x[i]);
    }
}

__global__ __launch_bounds__(256) void k_scalar_stats(const float* __restrict__ s,
                                                      float* __restrict__ stats) {
    __shared__ float ls[256], lq[256];
    float a = 0.f, b = 0.f;
    for (int i = blockIdx.x * blockDim.x + threadIdx.x; i < NN; i += gridDim.x * blockDim.x) {
        float v = s[i]; a += v; b += v * v;
    }
    ls[threadIdx.x] = a; lq[threadIdx.x] = b; __syncthreads();
    for (int st = 128; st > 0; st >>= 1) {
        if (threadIdx.x < st) { ls[threadIdx.x] += ls[threadIdx.x + st]; lq[threadIdx.x] += lq[threadIdx.x + st]; }
        __syncthreads();
    }
    if (threadIdx.x == 0) { atomicAdd(&stats[0], ls[0]); atomicAdd(&stats[1], lq[0]); }
}

__global__ void k_l1_coeffs(const float* __restrict__ stats, const float* __restrict__ W1,
                            const float* __restrict__ b1, const float* __restrict__ g1,
                            const float* __restrict__ bt1,
                            float* __restrict__ alpha, float* __restrict__ cshift) {
    int j = threadIdx.x;
    if (j < FD) {
        float mean = stats[0] * (1.0f / NN);
        float var  = stats[1] * (1.0f / NN) - mean * mean;
        float w = W1[j];
        float rinv = rsqrtf(var * w * w + BN_EPS);
        float a = g1[j] * w * rinv;
        alpha[j]  = a;
        cshift[j] = bt1[j] - a * mean;
    }
}

__global__ void k_l1_apply(const float* __restrict__ s, const float* __restrict__ alpha,
                           const float* __restrict__ cshift, float* __restrict__ xo) {
    int t = blockIdx.x * blockDim.x + threadIdx.x;
    int i = t >> 6, j = t & 63;
    if (i < NN) xo[t] = fmaxf(alpha[j] * s[i] + cshift[j], 0.0f);
}

// ---------------- dense 64x64 matmul ----------------
__global__ __launch_bounds__(256) void k_matmul64(const float* __restrict__ x,
                                                  const float* __restrict__ W,
                                                  float* __restrict__ h) {
    __shared__ float Ws[64 * 64];
    __shared__ float xs[4 * 64];
    int t = threadIdx.x;
    for (int k = t; k < 64 * 64; k += 256) Ws[k] = W[k];
    int n0 = blockIdx.x * 4;
    int j = t & 63, n = t >> 6;
    int node = n0 + n;
    int gidx = n0 * 64 + t;
    xs[t] = (gidx < NN * 64) ? x[gidx] : 0.0f;
    __syncthreads();
    if (node < NN) {
        float acc = 0.f;
        #pragma unroll
        for (int k = 0; k < 64; ++k) acc += xs[n * 64 + k] * Ws[k * 64 + j];
        h[node * 64 + j] = acc;
    }
}

// ---------------- CSR gather aggregation (fused self-loop + bias) ----------------
// wave per dst node; 4 edges in flight (16 lanes x float4 each)
__global__ __launch_bounds__(256) void k_gather(const int* __restrict__ cursor,
                                                const int* __restrict__ eidx,
                                                const float* __restrict__ dinv,
                                                const float* __restrict__ h,
                                                const float* __restrict__ b,
                                                float* __restrict__ agg) {
    int node = blockIdx.x * 4 + (threadIdx.x >> 6);
    if (node >= NN) return;
    int lane = threadIdx.x & 63;
    int eslot = lane >> 4;          // 0..3
    int fb = (lane & 15) << 2;      // feature base 0..60
    int start = node ? cursor[node - 1] : 0;
    int end = cursor[node];
    float4 acc = make_float4(0.f, 0.f, 0.f, 0.f);
    for (int e = start + eslot; e < end; e += 4) {
        int r = eidx[e];
        float dr = dinv[r];
        const float4 hv = *reinterpret_cast<const float4*>(&h[r * 64 + fb]);
        acc.x += hv.x * dr; acc.y += hv.y * dr; acc.z += hv.z * dr; acc.w += hv.w * dr;
    }
    // reduce the 4 edge slots: lanes {l, l^16, l^32, l^48}
    acc.x += __shfl_xor(acc.x, 16); acc.y += __shfl_xor(acc.y, 16);
    acc.z += __shfl_xor(acc.z, 16); acc.w += __shfl_xor(acc.w, 16);
    acc.x += __shfl_xor(acc.x, 32); acc.y += __shfl_xor(acc.y, 32);
    acc.z += __shfl_xor(acc.z, 32); acc.w += __shfl_xor(acc.w, 32);
    if (lane < 16) {
        float dc = dinv[node];
        const float4 hv = *reinterpret_cast<const float4*>(&h[node * 64 + fb]);
        const float4 bv = *reinterpret_cast<const float4*>(&b[fb]);
        float4 o;
        o.x = dc * (acc.x + dc * hv.x) + bv.x;
        o.y = dc * (acc.y + dc * hv.y) + bv.y;
        o.z = dc * (acc.z + dc * hv.z) + bv.z;
        o.w = dc * (acc.w + dc * hv.w) + bv.w;
        *reinterpret_cast<float4*>(&agg[node * 64 + fb]) = o;
    }
}

// ---------------- batchnorm ----------------
__global__ __launch_bounds__(256) void k_bn_stats(const float* __restrict__ agg,
                                                  float* __restrict__ bnsum, float* __restrict__ bnsq) {
    __shared__ float ls[256], lq[256];
    int j = threadIdx.x & 63, nl = threadIdx.x >> 6;
    float a = 0.f, b = 0.f;
    for (int i = blockIdx.x * 4 + nl; i < NN; i += gridDim.x * 4) {
        float v = agg[i * 64 + j]; a += v; b += v * v;
    }
    ls[threadIdx.x] = a; lq[threadIdx.x] = b; __syncthreads();
    if (threadIdx.x < 128) { ls[threadIdx.x] += ls[threadIdx.x + 128]; lq[threadIdx.x] += lq[threadIdx.x + 128]; }
    __syncthreads();
    if (threadIdx.x < 64) {
        atomicAdd(&bnsum[j], ls[threadIdx.x] + ls[threadIdx.x + 64]);
        atomicAdd(&bnsq[j],  lq[threadIdx.x] + lq[threadIdx.x + 64]);
    }
}

__global__ void k_bn_finalize(const float* __restrict__ bnsum, const float* __restrict__ bnsq,
                              const float* __restrict__ g, const float* __restrict__ bt,
                              float* __restrict__ scale, float* __restrict__ shift) {
    int j = threadIdx.x;
    if (j < FD) {
        float mean = bnsum[j] * (1.0f / NN);
        float var  = bnsq[j] * (1.0f / NN) - mean * mean;
        float rinv = rsqrtf(var + BN_EPS);
        float sc = g[j] * rinv;
        scale[j] = sc;
        shift[j] = bt[j] - sc * mean;
    }
}

__global__ void k_bn_apply(const float* __restrict__ agg, const float* __restrict__ scale,
                           const float* __restrict__ shift, float* __restrict__ xo) {
    int t = blockIdx.x * blockDim.x + threadIdx.x;
    int i = t >> 6, j = t & 63;
    if (i < NN) xo[t] = fmaxf(scale[j] * agg[t] + shift[j], 0.0f);
}

// ---------------- pooling (segmented: batch is sorted) + FC ----------------
__global__ __launch_bounds__(256) void k_pool_seg(const float* __restrict__ x,
                                                  const int* __restrict__ batch,
                                                  float* __restrict__ pooled,
                                                  float* __restrict__ cnt) {
    const int wpb = 4;
    int wave = blockIdx.x * wpb + (threadIdx.x >> 6);
    int lane = threadIdx.x & 63;
    const int nwaves = gridDim.x * wpb;
    int chunk = (NN + nwaves - 1) / nwaves;
    int i0 = wave * chunk;
    int i1 = i0 + chunk; if (i1 > NN) i1 = NN;
    if (i0 >= NN) return;
    float acc = 0.0f;
    int curb = batch[i0];
    int runlen = 0;
    for (int i = i0; i < i1; ++i) {
        int b = batch[i];
        if (b != curb) {
            atomicAdd(&pooled[curb * 64 + lane], acc);
            if (lane == 0) atomicAdd(&cnt[curb], (float)runlen);
            acc = 0.0f; runlen = 0; curb = b;
        }
        acc += x[i * 64 + lane];
        ++runlen;
    }
    atomicAdd(&pooled[curb * 64 + lane], acc);
    if (lane == 0) atomicAdd(&cnt[curb], (float)runlen);
}

__global__ __launch_bounds__(128) void k_fc(const float* __restrict__ pooled, const float* __restrict__ cnt,
                                            const float* __restrict__ fw1, const float* __restrict__ fb1,
                                            const float* __restrict__ fw2, const float* __restrict__ fb2,
                                            float* __restrict__ out) {
    __shared__ float p[64], hsh[128];
    int g = blockIdx.x, t = threadIdx.x;
    if (t < 64) {
        float c = cnt[g]; c = c < 1.f ? 1.f : c;
        p[t] = pooled[g * 64 + t] / c;
    }
    __syncthreads();
    float acc = fb1[t];
    #pragma unroll 8
    for (int k = 0; k < 64; ++k) acc += p[k] * fw1[t * 64 + k];
    hsh[t] = fmaxf(acc, 0.f);
    __syncthreads();
    if (t < 10) {
        float o = fb2[t];
        #pragma unroll 8
        for (int k = 0; k < 128; ++k) o += hsh[k] * fw2[t * 128 + k];
        out[g * 10 + t] = o;
    }
}

// ---------------- launch ----------------
extern "C" void kernel_launch(void* const* d_in, const int* in_sizes, int n_in,
                              void* d_out, int out_size, void* d_ws, size_t ws_size,
                              hipStream_t stream) {
    const float* x   = (const float*)d_in[0];
    const int* ei    = (const int*)d_in[1];
    const int* batch = (const int*)d_in[2];
    const float* W[5]  = {nullptr, (const float*)d_in[3],  (const float*)d_in[7],
                                   (const float*)d_in[11], (const float*)d_in[15]};
    const float* bb[5] = {nullptr, (const float*)d_in[4],  (const float*)d_in[8],
                                   (const float*)d_in[12], (const float*)d_in[16]};
    const float* gg[5] = {nullptr, (const float*)d_in[5],  (const float*)d_in[9],
                                   (const float*)d_in[13], (const float*)d_in[17]};
    const float* bt[5] = {nullptr, (const float*)d_in[6],  (const float*)d_in[10],
                                   (const float*)d_in[14], (const float*)d_in[18]};
    const float* fw1 = (const float*)d_in[19];
    const float* fb1 = (const float*)d_in[20];
    const float* fw2 = (const float*)d_in[21];
    const float* fb2 = (const float*)d_in[22];
    float* out = (float*)d_out;

    const int* row = ei;
    const int* col = ei + NE;

    float* ws = (float*)d_ws;
    float* dinv    = ws + 0;          // N (int deg, then float dinv in place)
    int*   degi    = (int*)dinv;
    int*   cursor  = (int*)(ws + 50000);   // N
    int*   eidx    = (int*)(ws + 100000);  // E
    float* s       = ws + 900000;     // N
    float* stats   = ws + 950000;     // 2
    float* bnsum   = ws + 950064;
    float* bnsq    = ws + 950128;
    float* scale   = ws + 950192;
    float* shift   = ws + 950256;
    float* pooled  = ws + 950400;     // 64*64
    float* cnt     = ws + 954496;     // 64
    float* xbuf    = ws + 1000000;    // N*64
    float* hbuf    = ws + 4200000;    // N*64
    float* aggbuf  = ws + 7400000;    // N*64

    const int B = 256;
    int gE  = (NE + B - 1) / B;
    int gN  = (NN + B - 1) / B;
    int gNF = (NN * 64 + B - 1) / B;

    // CSR build + dinv
    hipMemsetAsync(degi, 0, NN * sizeof(int), stream);
    k_hist<<<gE, B, 0, stream>>>(col, degi);
    k_scan<<<1, 1024, 0, stream>>>(degi, cursor);
    k_dinv<<<gN, B, 0, stream>>>(degi);
    k_fill<<<gE, B, 0, stream>>>(row, col, cursor, eidx);

    // layer 1 (scalar propagation + folded BN)
    k_l1_gather<<<gN, B, 0, stream>>>(cursor, eidx, dinv, x, s);
    hipMemsetAsync(stats, 0, 2 * sizeof(float), stream);
    k_scalar_stats<<<256, B, 0, stream>>>(s, stats);
    k_l1_coeffs<<<1, 64, 0, stream>>>(stats, W[1], bb[1], gg[1], bt[1], scale, shift);
    k_l1_apply<<<gNF, B, 0, stream>>>(s, scale, shift, xbuf);

    // layers 2..4
    for (int L = 2; L <= 4; ++L) {
        k_matmul64<<<(NN + 3) / 4, B, 0, stream>>>(xbuf, W[L], hbuf);
        k_gather<<<(NN + 3) / 4, B, 0, stream>>>(cursor, eidx, dinv, hbuf, bb[L], aggbuf);
        hipMemsetAsync(bnsum, 0, 128 * sizeof(float), stream);
        k_bn_stats<<<512, B, 0, stream>>>(aggbuf, bnsum, bnsq);
        k_bn_finalize<<<1, 64, 0, stream>>>(bnsum, bnsq, gg[L], bt[L], scale, shift);
        k_bn_apply<<<gNF, B, 0, stream>>>(aggbuf, scale, shift, xbuf);
    }

    // pool (segmented) + FC
    hipMemsetAsync(pooled, 0, (64 * 64 + 64) * sizeof(float), stream);
    k_pool_seg<<<512, B, 0, stream>>>(xbuf, batch, pooled, cnt);
    k_fc<<<NG, 128, 0, stream>>>(pooled, cnt, fw1, fb1, fw2, fb2, out);
}

// Round 4
// 442.080 us; speedup vs baseline: 2.7440x; 1.1944x over previous
//
#include <hip/hip_runtime.h>

#define NN 50000
#define NE 800000
#define NG 64
#define FD 64
#define BN_EPS 1e-5f
#define SCAN_B 256
#define SCAN_NBLK ((NN + SCAN_B - 1) / SCAN_B)   // 196

// ---------------- CSR build ----------------
__global__ void k_hist(const int* __restrict__ col, int* __restrict__ deg) {
    int e = blockIdx.x * blockDim.x + threadIdx.x;
    if (e < NE) atomicAdd(&deg[col[e]], 1);
}

// phase 1: per-block inclusive scan -> exclusive offsets within block + block sums
__global__ __launch_bounds__(SCAN_B) void k_scan_blk(const int* __restrict__ deg,
                                                     int* __restrict__ cursor,
                                                     int* __restrict__ bsum) {
    __shared__ int sh[SCAN_B];
    int b = blockIdx.x, t = threadIdx.x;
    int i = b * SCAN_B + t;
    int v = (i < NN) ? deg[i] : 0;
    sh[t] = v;
    __syncthreads();
    for (int off = 1; off < SCAN_B; off <<= 1) {
        int u = (t >= off) ? sh[t - off] : 0;
        __syncthreads();
        sh[t] += u;
        __syncthreads();
    }
    if (i < NN) cursor[i] = sh[t] - v;   // exclusive within block
    if (t == SCAN_B - 1) bsum[b] = sh[t];
}

// phase 2: scan the block sums (196 values) -> exclusive block offsets
__global__ __launch_bounds__(SCAN_B) void k_scan_top(int* __restrict__ bsum) {
    __shared__ int sh[SCAN_B];
    int t = threadIdx.x;
    int v = (t < SCAN_NBLK) ? bsum[t] : 0;
    sh[t] = v;
    __syncthreads();
    for (int off = 1; off < SCAN_B; off <<= 1) {
        int u = (t >= off) ? sh[t - off] : 0;
        __syncthreads();
        sh[t] += u;
        __syncthreads();
    }
    if (t < SCAN_NBLK) bsum[t] = sh[t] - v;  // exclusive
}

// phase 3: add block offsets
__global__ __launch_bounds__(SCAN_B) void k_scan_add(int* __restrict__ cursor,
                                                     const int* __restrict__ bsum) {
    int b = blockIdx.x, t = threadIdx.x;
    int i = b * SCAN_B + t;
    if (i < NN) cursor[i] += bsum[b];
}

// deg(int) -> dinv(float) in place
__global__ void k_dinv(int* __restrict__ degi) {
    int i = blockIdx.x * blockDim.x + threadIdx.x;
    if (i < NN) {
        float d = (float)degi[i];
        ((float*)degi)[i] = rsqrtf(d + 1.0f);
    }
}

// fill eidx; afterwards cursor[i] = inclusive end of bucket i
__global__ void k_fill(const int* __restrict__ row, const int* __restrict__ col,
                       int* __restrict__ cursor, int* __restrict__ eidx) {
    int e = blockIdx.x * blockDim.x + threadIdx.x;
    if (e < NE) {
        int pos = atomicAdd(&cursor[col[e]], 1);
        eidx[pos] = row[e];
    }
}

// ---------------- layer 1: scalar propagation via CSR gather ----------------
__global__ void k_l1_gather(const int* __restrict__ cursor, const int* __restrict__ eidx,
                            const float* __restrict__ dinv, const float* __restrict__ x,
                            float* __restrict__ s) {
    int i = blockIdx.x * blockDim.x + threadIdx.x;
    if (i < NN) {
        int start = i ? cursor[i - 1] : 0;
        int end = cursor[i];
        float acc = 0.0f;
        for (int k = start; k < end; ++k) {
            int r = eidx[k];
            acc += x[r] * dinv[r];
        }
        float di = dinv[i];
        s[i] = di * (acc + di * x[i]);
    }
}

__global__ __launch_bounds__(256) void k_scalar_stats(const float* __restrict__ s,
                                                      float* __restrict__ stats) {
    __shared__ float ls[256], lq[256];
    float a = 0.f, b = 0.f;
    for (int i = blockIdx.x * blockDim.x + threadIdx.x; i < NN; i += gridDim.x * blockDim.x) {
        float v = s[i]; a += v; b += v * v;
    }
    ls[threadIdx.x] = a; lq[threadIdx.x] = b; __syncthreads();
    for (int st = 128; st > 0; st >>= 1) {
        if (threadIdx.x < st) { ls[threadIdx.x] += ls[threadIdx.x + st]; lq[threadIdx.x] += lq[threadIdx.x + st]; }
        __syncthreads();
    }
    if (threadIdx.x == 0) { atomicAdd(&stats[0], ls[0]); atomicAdd(&stats[1], lq[0]); }
}

__global__ void k_l1_coeffs(const float* __restrict__ stats, const float* __restrict__ W1,
                            const float* __restrict__ b1, const float* __restrict__ g1,
                            const float* __restrict__ bt1,
                            float* __restrict__ alpha, float* __restrict__ cshift) {
    int j = threadIdx.x;
    if (j < FD) {
        float mean = stats[0] * (1.0f / NN);
        float var  = stats[1] * (1.0f / NN) - mean * mean;
        float w = W1[j];
        float rinv = rsqrtf(var * w * w + BN_EPS);
        float a = g1[j] * w * rinv;
        alpha[j]  = a;
        cshift[j] = bt1[j] - a * mean;
    }
}

__global__ void k_l1_apply(const float* __restrict__ s, const float* __restrict__ alpha,
                           const float* __restrict__ cshift, float* __restrict__ xo) {
    int t = blockIdx.x * blockDim.x + threadIdx.x;
    int i = t >> 6, j = t & 63;
    if (i < NN) xo[t] = fmaxf(alpha[j] * s[i] + cshift[j], 0.0f);
}

// ---------------- dense 64x64 matmul ----------------
__global__ __launch_bounds__(256) void k_matmul64(const float* __restrict__ x,
                                                  const float* __restrict__ W,
                                                  float* __restrict__ h) {
    __shared__ float Ws[64 * 64];
    __shared__ float xs[4 * 64];
    int t = threadIdx.x;
    for (int k = t; k < 64 * 64; k += 256) Ws[k] = W[k];
    int n0 = blockIdx.x * 4;
    int j = t & 63, n = t >> 6;
    int node = n0 + n;
    int gidx = n0 * 64 + t;
    xs[t] = (gidx < NN * 64) ? x[gidx] : 0.0f;
    __syncthreads();
    if (node < NN) {
        float acc = 0.f;
        #pragma unroll
        for (int k = 0; k < 64; ++k) acc += xs[n * 64 + k] * Ws[k * 64 + j];
        h[node * 64 + j] = acc;
    }
}

// ---------------- CSR gather aggregation (fused self-loop + bias) ----------------
__global__ __launch_bounds__(256) void k_gather(const int* __restrict__ cursor,
                                                const int* __restrict__ eidx,
                                                const float* __restrict__ dinv,
                                                const float* __restrict__ h,
                                                const float* __restrict__ b,
                                                float* __restrict__ agg) {
    int node = blockIdx.x * 4 + (threadIdx.x >> 6);
    if (node >= NN) return;
    int lane = threadIdx.x & 63;
    int eslot = lane >> 4;          // 0..3
    int fb = (lane & 15) << 2;      // feature base 0..60
    int start = node ? cursor[node - 1] : 0;
    int end = cursor[node];
    float4 acc = make_float4(0.f, 0.f, 0.f, 0.f);
    for (int e = start + eslot; e < end; e += 4) {
        int r = eidx[e];
        float dr = dinv[r];
        const float4 hv = *reinterpret_cast<const float4*>(&h[r * 64 + fb]);
        acc.x += hv.x * dr; acc.y += hv.y * dr; acc.z += hv.z * dr; acc.w += hv.w * dr;
    }
    acc.x += __shfl_xor(acc.x, 16); acc.y += __shfl_xor(acc.y, 16);
    acc.z += __shfl_xor(acc.z, 16); acc.w += __shfl_xor(acc.w, 16);
    acc.x += __shfl_xor(acc.x, 32); acc.y += __shfl_xor(acc.y, 32);
    acc.z += __shfl_xor(acc.z, 32); acc.w += __shfl_xor(acc.w, 32);
    if (lane < 16) {
        float dc = dinv[node];
        const float4 hv = *reinterpret_cast<const float4*>(&h[node * 64 + fb]);
        const float4 bv = *reinterpret_cast<const float4*>(&b[fb]);
        float4 o;
        o.x = dc * (acc.x + dc * hv.x) + bv.x;
        o.y = dc * (acc.y + dc * hv.y) + bv.y;
        o.z = dc * (acc.z + dc * hv.z) + bv.z;
        o.w = dc * (acc.w + dc * hv.w) + bv.w;
        *reinterpret_cast<float4*>(&agg[node * 64 + fb]) = o;
    }
}

// ---------------- batchnorm ----------------
__global__ __launch_bounds__(256) void k_bn_stats(const float* __restrict__ agg,
                                                  float* __restrict__ bnsum, float* __restrict__ bnsq) {
    __shared__ float ls[256], lq[256];
    int j = threadIdx.x & 63, nl = threadIdx.x >> 6;
    float a = 0.f, b = 0.f;
    for (int i = blockIdx.x * 4 + nl; i < NN; i += gridDim.x * 4) {
        float v = agg[i * 64 + j]; a += v; b += v * v;
    }
    ls[threadIdx.x] = a; lq[threadIdx.x] = b; __syncthreads();
    if (threadIdx.x < 128) { ls[threadIdx.x] += ls[threadIdx.x + 128]; lq[threadIdx.x] += lq[threadIdx.x + 128]; }
    __syncthreads();
    if (threadIdx.x < 64) {
        atomicAdd(&bnsum[j], ls[threadIdx.x] + ls[threadIdx.x + 64]);
        atomicAdd(&bnsq[j],  lq[threadIdx.x] + lq[threadIdx.x + 64]);
    }
}

__global__ void k_bn_finalize(const float* __restrict__ bnsum, const float* __restrict__ bnsq,
                              const float* __restrict__ g, const float* __restrict__ bt,
                              float* __restrict__ scale, float* __restrict__ shift) {
    int j = threadIdx.x;
    if (j < FD) {
        float mean = bnsum[j] * (1.0f / NN);
        float var  = bnsq[j] * (1.0f / NN) - mean * mean;
        float rinv = rsqrtf(var + BN_EPS);
        float sc = g[j] * rinv;
        scale[j] = sc;
        shift[j] = bt[j] - sc * mean;
    }
}

__global__ void k_bn_apply(const float* __restrict__ agg, const float* __restrict__ scale,
                           const float* __restrict__ shift, float* __restrict__ xo) {
    int t = blockIdx.x * blockDim.x + threadIdx.x;
    int i = t >> 6, j = t & 63;
    if (i < NN) xo[t] = fmaxf(scale[j] * agg[t] + shift[j], 0.0f);
}

// ---------------- pooling (segmented) + FC ----------------
__global__ __launch_bounds__(256) void k_pool_seg(const float* __restrict__ x,
                                                  const int* __restrict__ batch,
                                                  float* __restrict__ pooled,
                                                  float* __restrict__ cnt) {
    const int wpb = 4;
    int wave = blockIdx.x * wpb + (threadIdx.x >> 6);
    int lane = threadIdx.x & 63;
    const int nwaves = gridDim.x * wpb;
    int chunk = (NN + nwaves - 1) / nwaves;
    int i0 = wave * chunk;
    int i1 = i0 + chunk; if (i1 > NN) i1 = NN;
    if (i0 >= NN) return;
    float acc = 0.0f;
    int curb = batch[i0];
    int runlen = 0;
    for (int i = i0; i < i1; ++i) {
        int b = batch[i];
        if (b != curb) {
            atomicAdd(&pooled[curb * 64 + lane], acc);
            if (lane == 0) atomicAdd(&cnt[curb], (float)runlen);
            acc = 0.0f; runlen = 0; curb = b;
        }
        acc += x[i * 64 + lane];
        ++runlen;
    }
    atomicAdd(&pooled[curb * 64 + lane], acc);
    if (lane == 0) atomicAdd(&cnt[curb], (float)runlen);
}

__global__ __launch_bounds__(128) void k_fc(const float* __restrict__ pooled, const float* __restrict__ cnt,
                                            const float* __restrict__ fw1, const float* __restrict__ fb1,
                                            const float* __restrict__ fw2, const float* __restrict__ fb2,
                                            float* __restrict__ out) {
    __shared__ float p[64], hsh[128];
    int g = blockIdx.x, t = threadIdx.x;
    if (t < 64) {
        float c = cnt[g]; c = c < 1.f ? 1.f : c;
        p[t] = pooled[g * 64 + t] / c;
    }
    __syncthreads();
    float acc = fb1[t];
    #pragma unroll 8
    for (int k = 0; k < 64; ++k) acc += p[k] * fw1[t * 64 + k];
    hsh[t] = fmaxf(acc, 0.f);
    __syncthreads();
    if (t < 10) {
        float o = fb2[t];
        #pragma unroll 8
        for (int k = 0; k < 128; ++k) o += hsh[k] * fw2[t * 128 + k];
        out[g * 10 + t] = o;
    }
}

// ---------------- launch ----------------
extern "C" void kernel_launch(void* const* d_in, const int* in_sizes, int n_in,
                              void* d_out, int out_size, void* d_ws, size_t ws_size,
                              hipStream_t stream) {
    const float* x   = (const float*)d_in[0];
    const int* ei    = (const int*)d_in[1];
    const int* batch = (const int*)d_in[2];
    const float* W[5]  = {nullptr, (const float*)d_in[3],  (const float*)d_in[7],
                                   (const float*)d_in[11], (const float*)d_in[15]};
    const float* bb[5] = {nullptr, (const float*)d_in[4],  (const float*)d_in[8],
                                   (const float*)d_in[12], (const float*)d_in[16]};
    const float* gg[5] = {nullptr, (const float*)d_in[5],  (const float*)d_in[9],
                                   (const float*)d_in[13], (const float*)d_in[17]};
    const float* bt[5] = {nullptr, (const float*)d_in[6],  (const float*)d_in[10],
                                   (const float*)d_in[14], (const float*)d_in[18]};
    const float* fw1 = (const float*)d_in[19];
    const float* fb1 = (const float*)d_in[20];
    const float* fw2 = (const float*)d_in[21];
    const float* fb2 = (const float*)d_in[22];
    float* out = (float*)d_out;

    const int* row = ei;
    const int* col = ei + NE;

    float* ws = (float*)d_ws;
    float* dinv    = ws + 0;               // N (int deg, then float dinv in place)
    int*   degi    = (int*)dinv;
    int*   cursor  = (int*)(ws + 50000);   // N
    int*   eidx    = (int*)(ws + 100000);  // E
    int*   bsum    = (int*)(ws + 900000);  // SCAN_NBLK
    float* s       = ws + 901000;          // N
    float* stats   = ws + 951008;
    float* bnsum   = ws + 951072;
    float* bnsq    = ws + 951136;
    float* scale   = ws + 951200;
    float* shift   = ws + 951264;
    float* pooled  = ws + 951360;          // 64*64
    float* cnt     = ws + 955456;          // 64
    float* xbuf    = ws + 1000000;         // N*64
    float* hbuf    = ws + 4200000;         // N*64
    float* aggbuf  = ws + 7400000;         // N*64

    const int B = 256;
    int gE  = (NE + B - 1) / B;
    int gN  = (NN + B - 1) / B;
    int gNF = (NN * 64 + B - 1) / B;

    // CSR build + dinv
    hipMemsetAsync(degi, 0, NN * sizeof(int), stream);
    k_hist<<<gE, B, 0, stream>>>(col, degi);
    k_scan_blk<<<SCAN_NBLK, SCAN_B, 0, stream>>>(degi, cursor, bsum);
    k_scan_top<<<1, SCAN_B, 0, stream>>>(bsum);
    k_scan_add<<<SCAN_NBLK, SCAN_B, 0, stream>>>(cursor, bsum);
    k_dinv<<<gN, B, 0, stream>>>(degi);
    k_fill<<<gE, B, 0, stream>>>(row, col, cursor, eidx);

    // layer 1 (scalar propagation + folded BN)
    k_l1_gather<<<gN, B, 0, stream>>>(cursor, eidx, dinv, x, s);
    hipMemsetAsync(stats, 0, 2 * sizeof(float), stream);
    k_scalar_stats<<<256, B, 0, stream>>>(s, stats);
    k_l1_coeffs<<<1, 64, 0, stream>>>(stats, W[1], bb[1], gg[1], bt[1], scale, shift);
    k_l1_apply<<<gNF, B, 0, stream>>>(s, scale, shift, xbuf);

    // layers 2..4
    for (int L = 2; L <= 4; ++L) {
        k_matmul64<<<(NN + 3) / 4, B, 0, stream>>>(xbuf, W[L], hbuf);
        k_gather<<<(NN + 3) / 4, B, 0, stream>>>(cursor, eidx, dinv, hbuf, bb[L], aggbuf);
        hipMemsetAsync(bnsum, 0, 128 * sizeof(float), stream);
        k_bn_stats<<<512, B, 0, stream>>>(aggbuf, bnsum, bnsq);
        k_bn_finalize<<<1, 64, 0, stream>>>(bnsum, bnsq, gg[L], bt[L], scale, shift);
        k_bn_apply<<<gNF, B, 0, stream>>>(aggbuf, scale, shift, xbuf);
    }

    // pool (segmented) + FC
    hipMemsetAsync(pooled, 0, (64 * 64 + 64) * sizeof(float), stream);
    k_pool_seg<<<512, B, 0, stream>>>(xbuf, batch, pooled, cnt);
    k_fc<<<NG, 128, 0, stream>>>(pooled, cnt, fw1, fb1, fw2, fb2, out);
}

// Round 5
// 405.676 us; speedup vs baseline: 2.9903x; 1.0897x over previous
//
#include <hip/hip_runtime.h>

#define NN 50000
#define NE 800000
#define NG 64
#define FD 64
#define BN_EPS 1e-5f
#define SCAN_B 256
#define SCAN_NBLK ((NN + SCAN_B - 1) / SCAN_B)   // 196

// ---------------- CSR build ----------------
__global__ void k_hist(const int* __restrict__ col, int* __restrict__ deg) {
    int e = blockIdx.x * blockDim.x + threadIdx.x;
    if (e < NE) atomicAdd(&deg[col[e]], 1);
}

// phase 1: per-block scan -> exclusive offsets within block + block sums; also dinv
__global__ __launch_bounds__(SCAN_B) void k_scan_blk(const int* __restrict__ deg,
                                                     int* __restrict__ cursor,
                                                     int* __restrict__ bsum,
                                                     float* __restrict__ dinv) {
    __shared__ int sh[SCAN_B];
    int b = blockIdx.x, t = threadIdx.x;
    int i = b * SCAN_B + t;
    int v = (i < NN) ? deg[i] : 0;
    if (i < NN) dinv[i] = rsqrtf((float)v + 1.0f);
    sh[t] = v;
    __syncthreads();
    for (int off = 1; off < SCAN_B; off <<= 1) {
        int u = (t >= off) ? sh[t - off] : 0;
        __syncthreads();
        sh[t] += u;
        __syncthreads();
    }
    if (i < NN) cursor[i] = sh[t] - v;   // exclusive within block
    if (t == SCAN_B - 1) bsum[b] = sh[t];
}

// phase 2: scan the block sums (196 values) -> exclusive block offsets
__global__ __launch_bounds__(SCAN_B) void k_scan_top(int* __restrict__ bsum) {
    __shared__ int sh[SCAN_B];
    int t = threadIdx.x;
    int v = (t < SCAN_NBLK) ? bsum[t] : 0;
    sh[t] = v;
    __syncthreads();
    for (int off = 1; off < SCAN_B; off <<= 1) {
        int u = (t >= off) ? sh[t - off] : 0;
        __syncthreads();
        sh[t] += u;
        __syncthreads();
    }
    if (t < SCAN_NBLK) bsum[t] = sh[t] - v;  // exclusive
}

// phase 3: add block offsets
__global__ __launch_bounds__(SCAN_B) void k_scan_add(int* __restrict__ cursor,
                                                     const int* __restrict__ bsum) {
    int b = blockIdx.x, t = threadIdx.x;
    int i = b * SCAN_B + t;
    if (i < NN) cursor[i] += bsum[b];
}

// fill eidx; afterwards cursor[i] = inclusive end of bucket i
__global__ void k_fill(const int* __restrict__ row, const int* __restrict__ col,
                       int* __restrict__ cursor, int* __restrict__ eidx) {
    int e = blockIdx.x * blockDim.x + threadIdx.x;
    if (e < NE) {
        int pos = atomicAdd(&cursor[col[e]], 1);
        eidx[pos] = row[e];
    }
}

// ---------------- layer 1: scalar propagation via CSR gather ----------------
__global__ void k_l1_gather(const int* __restrict__ cursor, const int* __restrict__ eidx,
                            const float* __restrict__ dinv, const float* __restrict__ x,
                            float* __restrict__ s) {
    int i = blockIdx.x * blockDim.x + threadIdx.x;
    if (i < NN) {
        int start = i ? cursor[i - 1] : 0;
        int end = cursor[i];
        float acc = 0.0f;
        for (int k = start; k < end; ++k) {
            int r = eidx[k];
            acc += x[r] * dinv[r];
        }
        float di = dinv[i];
        s[i] = di * (acc + di * x[i]);
    }
}

__global__ __launch_bounds__(256) void k_scalar_stats(const float* __restrict__ s,
                                                      float* __restrict__ stats) {
    __shared__ float ls[256], lq[256];
    float a = 0.f, b = 0.f;
    for (int i = blockIdx.x * blockDim.x + threadIdx.x; i < NN; i += gridDim.x * blockDim.x) {
        float v = s[i]; a += v; b += v * v;
    }
    ls[threadIdx.x] = a; lq[threadIdx.x] = b; __syncthreads();
    for (int st = 128; st > 0; st >>= 1) {
        if (threadIdx.x < st) { ls[threadIdx.x] += ls[threadIdx.x + st]; lq[threadIdx.x] += lq[threadIdx.x + st]; }
        __syncthreads();
    }
    if (threadIdx.x == 0) { atomicAdd(&stats[0], ls[0]); atomicAdd(&stats[1], lq[0]); }
}

__global__ void k_l1_coeffs(const float* __restrict__ stats, const float* __restrict__ W1,
                            const float* __restrict__ b1, const float* __restrict__ g1,
                            const float* __restrict__ bt1,
                            float* __restrict__ alpha, float* __restrict__ cshift) {
    int j = threadIdx.x;
    if (j < FD) {
        float mean = stats[0] * (1.0f / NN);
        float var  = stats[1] * (1.0f / NN) - mean * mean;
        float w = W1[j];
        float rinv = rsqrtf(var * w * w + BN_EPS);
        float a = g1[j] * w * rinv;
        alpha[j]  = a;
        cshift[j] = bt1[j] - a * mean;
    }
}

// ---------------- fused activation + 64x64 matmul ----------------
// layer 2: x-tile built from scalar s: relu(alpha_j * s_i + c_j)
__global__ __launch_bounds__(256) void k_mm_l1(const float* __restrict__ s,
                                               const float* __restrict__ alpha,
                                               const float* __restrict__ cshift,
                                               const float* __restrict__ W,
                                               float* __restrict__ h) {
    __shared__ float Ws[64 * 64];
    __shared__ float xs[4 * 64];
    int t = threadIdx.x;
    for (int k = t; k < 64 * 64; k += 256) Ws[k] = W[k];
    int n0 = blockIdx.x * 4;
    int j = t & 63, n = t >> 6;
    int node = n0 + n;
    float sv = (node < NN) ? s[node] : 0.0f;
    xs[t] = fmaxf(alpha[j] * sv + cshift[j], 0.0f);
    __syncthreads();
    if (node < NN) {
        float acc = 0.f;
        #pragma unroll
        for (int k = 0; k < 64; ++k) acc += xs[n * 64 + k] * Ws[k * 64 + j];
        h[node * 64 + j] = acc;
    }
}

// layers 3,4: x-tile built from agg with BN+relu applied in-register
__global__ __launch_bounds__(256) void k_mm_bn(const float* __restrict__ src,
                                               const float* __restrict__ scale,
                                               const float* __restrict__ shift,
                                               const float* __restrict__ W,
                                               float* __restrict__ h) {
    __shared__ float Ws[64 * 64];
    __shared__ float xs[4 * 64];
    int t = threadIdx.x;
    for (int k = t; k < 64 * 64; k += 256) Ws[k] = W[k];
    int n0 = blockIdx.x * 4;
    int j = t & 63, n = t >> 6;
    int node = n0 + n;
    int gidx = n0 * 64 + t;
    float v = (gidx < NN * 64) ? src[gidx] : 0.0f;
    xs[t] = fmaxf(scale[j] * v + shift[j], 0.0f);
    __syncthreads();
    if (node < NN) {
        float acc = 0.f;
        #pragma unroll
        for (int k = 0; k < 64; ++k) acc += xs[n * 64 + k] * Ws[k * 64 + j];
        h[node * 64 + j] = acc;
    }
}

// ---------------- CSR gather aggregation (fused self-loop + bias) ----------------
__global__ __launch_bounds__(256) void k_gather(const int* __restrict__ cursor,
                                                const int* __restrict__ eidx,
                                                const float* __restrict__ dinv,
                                                const float* __restrict__ h,
                                                const float* __restrict__ b,
                                                float* __restrict__ agg) {
    int node = blockIdx.x * 4 + (threadIdx.x >> 6);
    if (node >= NN) return;
    int lane = threadIdx.x & 63;
    int eslot = lane >> 4;          // 0..3
    int fb = (lane & 15) << 2;      // feature base 0..60
    int start = node ? cursor[node - 1] : 0;
    int end = cursor[node];
    float4 acc = make_float4(0.f, 0.f, 0.f, 0.f);
    for (int e = start + eslot; e < end; e += 4) {
        int r = eidx[e];
        float dr = dinv[r];
        const float4 hv = *reinterpret_cast<const float4*>(&h[r * 64 + fb]);
        acc.x += hv.x * dr; acc.y += hv.y * dr; acc.z += hv.z * dr; acc.w += hv.w * dr;
    }
    acc.x += __shfl_xor(acc.x, 16); acc.y += __shfl_xor(acc.y, 16);
    acc.z += __shfl_xor(acc.z, 16); acc.w += __shfl_xor(acc.w, 16);
    acc.x += __shfl_xor(acc.x, 32); acc.y += __shfl_xor(acc.y, 32);
    acc.z += __shfl_xor(acc.z, 32); acc.w += __shfl_xor(acc.w, 32);
    if (lane < 16) {
        float dc = dinv[node];
        const float4 hv = *reinterpret_cast<const float4*>(&h[node * 64 + fb]);
        const float4 bv = *reinterpret_cast<const float4*>(&b[fb]);
        float4 o;
        o.x = dc * (acc.x + dc * hv.x) + bv.x;
        o.y = dc * (acc.y + dc * hv.y) + bv.y;
        o.z = dc * (acc.z + dc * hv.z) + bv.z;
        o.w = dc * (acc.w + dc * hv.w) + bv.w;
        *reinterpret_cast<float4*>(&agg[node * 64 + fb]) = o;
    }
}

// ---------------- batchnorm stats ----------------
__global__ __launch_bounds__(256) void k_bn_stats(const float* __restrict__ agg,
                                                  float* __restrict__ bnsum, float* __restrict__ bnsq) {
    __shared__ float ls[256], lq[256];
    int j = threadIdx.x & 63, nl = threadIdx.x >> 6;
    float a = 0.f, b = 0.f;
    for (int i = blockIdx.x * 4 + nl; i < NN; i += gridDim.x * 4) {
        float v = agg[i * 64 + j]; a += v; b += v * v;
    }
    ls[threadIdx.x] = a; lq[threadIdx.x] = b; __syncthreads();
    if (threadIdx.x < 128) { ls[threadIdx.x] += ls[threadIdx.x + 128]; lq[threadIdx.x] += lq[threadIdx.x + 128]; }
    __syncthreads();
    if (threadIdx.x < 64) {
        atomicAdd(&bnsum[j], ls[threadIdx.x] + ls[threadIdx.x + 64]);
        atomicAdd(&bnsq[j],  lq[threadIdx.x] + lq[threadIdx.x + 64]);
    }
}

__global__ void k_bn_finalize(const float* __restrict__ bnsum, const float* __restrict__ bnsq,
                              const float* __restrict__ g, const float* __restrict__ bt,
                              float* __restrict__ scale, float* __restrict__ shift) {
    int j = threadIdx.x;
    if (j < FD) {
        float mean = bnsum[j] * (1.0f / NN);
        float var  = bnsq[j] * (1.0f / NN) - mean * mean;
        float rinv = rsqrtf(var + BN_EPS);
        float sc = g[j] * rinv;
        scale[j] = sc;
        shift[j] = bt[j] - sc * mean;
    }
}

// ---------------- fused BN + pooling (segmented) ----------------
__global__ __launch_bounds__(256) void k_pool_bn(const float* __restrict__ agg,
                                                 const float* __restrict__ scale,
                                                 const float* __restrict__ shift,
                                                 const int* __restrict__ batch,
                                                 float* __restrict__ pooled,
                                                 float* __restrict__ cnt) {
    const int wpb = 4;
    int wave = blockIdx.x * wpb + (threadIdx.x >> 6);
    int lane = threadIdx.x & 63;
    const int nwaves = gridDim.x * wpb;
    int chunk = (NN + nwaves - 1) / nwaves;
    int i0 = wave * chunk;
    int i1 = i0 + chunk; if (i1 > NN) i1 = NN;
    if (i0 >= NN) return;
    float sc = scale[lane], sh = shift[lane];
    float acc = 0.0f;
    int curb = batch[i0];
    int runlen = 0;
    for (int i = i0; i < i1; ++i) {
        int b = batch[i];
        if (b != curb) {
            atomicAdd(&pooled[curb * 64 + lane], acc);
            if (lane == 0) atomicAdd(&cnt[curb], (float)runlen);
            acc = 0.0f; runlen = 0; curb = b;
        }
        acc += fmaxf(sc * agg[i * 64 + lane] + sh, 0.0f);
        ++runlen;
    }
    atomicAdd(&pooled[curb * 64 + lane], acc);
    if (lane == 0) atomicAdd(&cnt[curb], (float)runlen);
}

__global__ __launch_bounds__(128) void k_fc(const float* __restrict__ pooled, const float* __restrict__ cnt,
                                            const float* __restrict__ fw1, const float* __restrict__ fb1,
                                            const float* __restrict__ fw2, const float* __restrict__ fb2,
                                            float* __restrict__ out) {
    __shared__ float p[64], hsh[128];
    int g = blockIdx.x, t = threadIdx.x;
    if (t < 64) {
        float c = cnt[g]; c = c < 1.f ? 1.f : c;
        p[t] = pooled[g * 64 + t] / c;
    }
    __syncthreads();
    float acc = fb1[t];
    #pragma unroll 8
    for (int k = 0; k < 64; ++k) acc += p[k] * fw1[t * 64 + k];
    hsh[t] = fmaxf(acc, 0.f);
    __syncthreads();
    if (t < 10) {
        float o = fb2[t];
        #pragma unroll 8
        for (int k = 0; k < 128; ++k) o += hsh[k] * fw2[t * 128 + k];
        out[g * 10 + t] = o;
    }
}

// ---------------- launch ----------------
extern "C" void kernel_launch(void* const* d_in, const int* in_sizes, int n_in,
                              void* d_out, int out_size, void* d_ws, size_t ws_size,
                              hipStream_t stream) {
    const float* x   = (const float*)d_in[0];
    const int* ei    = (const int*)d_in[1];
    const int* batch = (const int*)d_in[2];
    const float* W[5]  = {nullptr, (const float*)d_in[3],  (const float*)d_in[7],
                                   (const float*)d_in[11], (const float*)d_in[15]};
    const float* bb[5] = {nullptr, (const float*)d_in[4],  (const float*)d_in[8],
                                   (const float*)d_in[12], (const float*)d_in[16]};
    const float* gg[5] = {nullptr, (const float*)d_in[5],  (const float*)d_in[9],
                                   (const float*)d_in[13], (const float*)d_in[17]};
    const float* bt[5] = {nullptr, (const float*)d_in[6],  (const float*)d_in[10],
                                   (const float*)d_in[14], (const float*)d_in[18]};
    const float* fw1 = (const float*)d_in[19];
    const float* fb1 = (const float*)d_in[20];
    const float* fw2 = (const float*)d_in[21];
    const float* fb2 = (const float*)d_in[22];
    float* out = (float*)d_out;

    const int* row = ei;
    const int* col = ei + NE;

    float* ws = (float*)d_ws;
    int*   degi    = (int*)ws;              // N
    int*   cursor  = (int*)(ws + 50000);    // N
    int*   eidx    = (int*)(ws + 100000);   // E
    float* dinv    = ws + 900000;           // N
    int*   bsum    = (int*)(ws + 950000);   // SCAN_NBLK
    float* s       = ws + 951000;           // N
    float* stats   = ws + 1001008;
    float* bnsum   = ws + 1001072;
    float* bnsq    = ws + 1001136;
    float* scale   = ws + 1001200;
    float* shift   = ws + 1001264;
    float* pooled  = ws + 1001360;          // 64*64
    float* cnt     = ws + 1005456;          // 64
    float* hbuf    = ws + 1100000;          // N*64
    float* aggbuf  = ws + 4300000;          // N*64

    const int B = 256;
    int gE  = (NE + B - 1) / B;
    int gN  = (NN + B - 1) / B;

    // CSR build + dinv
    hipMemsetAsync(degi, 0, NN * sizeof(int), stream);
    k_hist<<<gE, B, 0, stream>>>(col, degi);
    k_scan_blk<<<SCAN_NBLK, SCAN_B, 0, stream>>>(degi, cursor, bsum, dinv);
    k_scan_top<<<1, SCAN_B, 0, stream>>>(bsum);
    k_scan_add<<<SCAN_NBLK, SCAN_B, 0, stream>>>(cursor, bsum);
    k_fill<<<gE, B, 0, stream>>>(row, col, cursor, eidx);

    // layer 1 (scalar propagation + folded BN)
    k_l1_gather<<<gN, B, 0, stream>>>(cursor, eidx, dinv, x, s);
    hipMemsetAsync(stats, 0, 2 * sizeof(float), stream);
    k_scalar_stats<<<256, B, 0, stream>>>(s, stats);
    k_l1_coeffs<<<1, 64, 0, stream>>>(stats, W[1], bb[1], gg[1], bt[1], scale, shift);

    // layer 2: fused l1-apply + matmul, gather, stats
    k_mm_l1<<<(NN + 3) / 4, B, 0, stream>>>(s, scale, shift, W[2], hbuf);
    k_gather<<<(NN + 3) / 4, B, 0, stream>>>(cursor, eidx, dinv, hbuf, bb[2], aggbuf);
    hipMemsetAsync(bnsum, 0, 128 * sizeof(float), stream);
    k_bn_stats<<<512, B, 0, stream>>>(aggbuf, bnsum, bnsq);
    k_bn_finalize<<<1, 64, 0, stream>>>(bnsum, bnsq, gg[2], bt[2], scale, shift);

    // layers 3,4: fused bn+matmul, gather, stats
    for (int L = 3; L <= 4; ++L) {
        k_mm_bn<<<(NN + 3) / 4, B, 0, stream>>>(aggbuf, scale, shift, W[L], hbuf);
        k_gather<<<(NN + 3) / 4, B, 0, stream>>>(cursor, eidx, dinv, hbuf, bb[L], aggbuf);
        hipMemsetAsync(bnsum, 0, 128 * sizeof(float), stream);
        k_bn_stats<<<512, B, 0, stream>>>(aggbuf, bnsum, bnsq);
        k_bn_finalize<<<1, 64, 0, stream>>>(bnsum, bnsq, gg[L], bt[L], scale, shift);
    }

    // fused BN + pool (segmented) + FC
    hipMemsetAsync(pooled, 0, (64 * 64 + 64) * sizeof(float), stream);
    k_pool_bn<<<512, B, 0, stream>>>(aggbuf, scale, shift, batch, pooled, cnt);
    k_fc<<<NG, 128, 0, stream>>>(pooled, cnt, fw1, fb1, fw2, fb2, out);
}

// Round 6
// 361.810 us; speedup vs baseline: 3.3528x; 1.1212x over previous
//
#include <hip/hip_runtime.h>

#define NN 50000
#define NE 800000
#define NG 64
#define FD 64
#define BN_EPS 1e-5f
#define SCAN_B 256
#define SCAN_NBLK ((NN + SCAN_B - 1) / SCAN_B)   // 196
#define NBIN 98            // ceil(50000/512)
#define BINCAP 12288       // expected ~8163/bin, >40 sigma headroom
#define SCH 4096
#define SCH_NBLK ((NE + SCH - 1) / SCH)          // 196

// ---------------- CSR build: binned two-pass ----------------
// pass A: in-block counting sort by bin, bulk append runs to per-bin regions
__global__ __launch_bounds__(256) void k_binscatter(const int* __restrict__ row,
                                                    const int* __restrict__ col,
                                                    int* __restrict__ gcnt,
                                                    int* __restrict__ bins) {
    __shared__ int stage[SCH];
    __shared__ int cnt[NBIN], off[NBIN + 1], cur[NBIN], gbase[NBIN];
    int t = threadIdx.x;
    int e0 = blockIdx.x * SCH;
    int nk = NE - e0; if (nk > SCH) nk = SCH;
    if (nk <= 0) return;
    for (int b = t; b < NBIN; b += 256) cnt[b] = 0;
    __syncthreads();
    for (int k = t; k < nk; k += 256) {
        int c = col[e0 + k];
        atomicAdd(&cnt[c >> 9], 1);
    }
    __syncthreads();
    if (t == 0) {
        int run = 0;
        for (int b = 0; b < NBIN; ++b) { off[b] = run; run += cnt[b]; }
        off[NBIN] = run;
    }
    __syncthreads();
    if (t < NBIN) {
        cur[t] = off[t];
        gbase[t] = t * BINCAP + atomicAdd(&gcnt[t], cnt[t]);
    }
    __syncthreads();
    for (int k = t; k < nk; k += 256) {
        int c = col[e0 + k];
        int r = row[e0 + k];
        int b = c >> 9;
        int pos = atomicAdd(&cur[b], 1);
        stage[pos] = ((c & 511) << 16) | r;
    }
    __syncthreads();
    for (int k = t; k < nk; k += 256) {
        int lo = 0, hi = NBIN - 1;          // largest b with off[b] <= k
        while (lo < hi) {
            int mid = (lo + hi + 1) >> 1;
            if (off[mid] <= k) lo = mid; else hi = mid - 1;
        }
        bins[gbase[lo] + (k - off[lo])] = stage[k];
    }
}

// pass B1: per-bin degree histogram (sequential reads, contiguous writes)
__global__ __launch_bounds__(256) void k_bindeg(const int* __restrict__ gcnt,
                                                const int* __restrict__ bins,
                                                int* __restrict__ deg) {
    __shared__ int ldeg[512];
    int b = blockIdx.x, t = threadIdx.x;
    for (int l = t; l < 512; l += 256) ldeg[l] = 0;
    __syncthreads();
    int nb = gcnt[b];
    const int* bp = bins + b * BINCAP;
    for (int k = t; k < nb; k += 256) atomicAdd(&ldeg[bp[k] >> 16], 1);
    __syncthreads();
    int base = b << 9;
    for (int l = t; l < 512; l += 256) {
        int i = base + l;
        if (i < NN) deg[i] = ldeg[l];
    }
}

// scan phase 1: per-block scan -> exclusive offsets within block + block sums; also dinv
__global__ __launch_bounds__(SCAN_B) void k_scan_blk(const int* __restrict__ deg,
                                                     int* __restrict__ cursor,
                                                     int* __restrict__ bsum,
                                                     float* __restrict__ dinv) {
    __shared__ int sh[SCAN_B];
    int b = blockIdx.x, t = threadIdx.x;
    int i = b * SCAN_B + t;
    int v = (i < NN) ? deg[i] : 0;
    if (i < NN) dinv[i] = rsqrtf((float)v + 1.0f);
    sh[t] = v;
    __syncthreads();
    for (int off = 1; off < SCAN_B; off <<= 1) {
        int u = (t >= off) ? sh[t - off] : 0;
        __syncthreads();
        sh[t] += u;
        __syncthreads();
    }
    if (i < NN) cursor[i] = sh[t] - v;
    if (t == SCAN_B - 1) bsum[b] = sh[t];
}

__global__ __launch_bounds__(SCAN_B) void k_scan_top(int* __restrict__ bsum) {
    __shared__ int sh[SCAN_B];
    int t = threadIdx.x;
    int v = (t < SCAN_NBLK) ? bsum[t] : 0;
    sh[t] = v;
    __syncthreads();
    for (int off = 1; off < SCAN_B; off <<= 1) {
        int u = (t >= off) ? sh[t - off] : 0;
        __syncthreads();
        sh[t] += u;
        __syncthreads();
    }
    if (t < SCAN_NBLK) bsum[t] = sh[t] - v;
}

__global__ __launch_bounds__(SCAN_B) void k_scan_add(int* __restrict__ cursor,
                                                     const int* __restrict__ bsum) {
    int b = blockIdx.x, t = threadIdx.x;
    int i = b * SCAN_B + t;
    if (i < NN) cursor[i] += bsum[b];
}

// pass B2: per-bin fill of eidx (contiguous ~32KB output range per block)
__global__ __launch_bounds__(256) void k_binfill(const int* __restrict__ gcnt,
                                                 const int* __restrict__ bins,
                                                 const int* __restrict__ cursor,
                                                 int* __restrict__ eidx) {
    __shared__ int lcur[512];
    int b = blockIdx.x, t = threadIdx.x;
    int base = b << 9;
    for (int l = t; l < 512; l += 256) {
        int i = base + l;
        lcur[l] = (i < NN) ? cursor[i] : 0;
    }
    __syncthreads();
    int nb = gcnt[b];
    const int* bp = bins + b * BINCAP;
    for (int k = t; k < nb; k += 256) {
        int v = bp[k];
        int pos = atomicAdd(&lcur[v >> 16], 1);
        eidx[pos] = v & 0xFFFF;
    }
}

// ---------------- layer 1: scalar propagation via CSR gather ----------------
__global__ void k_xd(const float* __restrict__ x, const float* __restrict__ dinv,
                     float* __restrict__ xd) {
    int i = blockIdx.x * blockDim.x + threadIdx.x;
    if (i < NN) xd[i] = x[i] * dinv[i];
}

__global__ void k_l1_gather(const int* __restrict__ cursor, const int* __restrict__ eidx,
                            const float* __restrict__ xd, const float* __restrict__ x,
                            const float* __restrict__ dinv, float* __restrict__ s) {
    int i = blockIdx.x * blockDim.x + threadIdx.x;
    if (i < NN) {
        int start = cursor[i];
        int end = (i < NN - 1) ? cursor[i + 1] : NE;
        float acc = 0.0f;
        for (int k = start; k < end; ++k) acc += xd[eidx[k]];
        float di = dinv[i];
        s[i] = di * (acc + di * x[i]);
    }
}

__global__ __launch_bounds__(256) void k_scalar_stats(const float* __restrict__ s,
                                                      float* __restrict__ stats) {
    __shared__ float ls[256], lq[256];
    float a = 0.f, b = 0.f;
    for (int i = blockIdx.x * blockDim.x + threadIdx.x; i < NN; i += gridDim.x * blockDim.x) {
        float v = s[i]; a += v; b += v * v;
    }
    ls[threadIdx.x] = a; lq[threadIdx.x] = b; __syncthreads();
    for (int st = 128; st > 0; st >>= 1) {
        if (threadIdx.x < st) { ls[threadIdx.x] += ls[threadIdx.x + st]; lq[threadIdx.x] += lq[threadIdx.x + st]; }
        __syncthreads();
    }
    if (threadIdx.x == 0) { atomicAdd(&stats[0], ls[0]); atomicAdd(&stats[1], lq[0]); }
}

__global__ void k_l1_coeffs(const float* __restrict__ stats, const float* __restrict__ W1,
                            const float* __restrict__ b1, const float* __restrict__ g1,
                            const float* __restrict__ bt1,
                            float* __restrict__ alpha, float* __restrict__ cshift) {
    int j = threadIdx.x;
    if (j < FD) {
        float mean = stats[0] * (1.0f / NN);
        float var  = stats[1] * (1.0f / NN) - mean * mean;
        float w = W1[j];
        float rinv = rsqrtf(var * w * w + BN_EPS);
        float a = g1[j] * w * rinv;
        alpha[j]  = a;
        cshift[j] = bt1[j] - a * mean;
    }
}

// ---------------- fused activation + 64x64 matmul ----------------
__global__ __launch_bounds__(256) void k_mm_l1(const float* __restrict__ s,
                                               const float* __restrict__ alpha,
                                               const float* __restrict__ cshift,
                                               const float* __restrict__ W,
                                               float* __restrict__ h) {
    __shared__ float Ws[64 * 64];
    __shared__ float xs[4 * 64];
    int t = threadIdx.x;
    for (int k = t; k < 64 * 64; k += 256) Ws[k] = W[k];
    int n0 = blockIdx.x * 4;
    int j = t & 63, n = t >> 6;
    int node = n0 + n;
    float sv = (node < NN) ? s[node] : 0.0f;
    xs[t] = fmaxf(alpha[j] * sv + cshift[j], 0.0f);
    __syncthreads();
    if (node < NN) {
        float acc = 0.f;
        #pragma unroll
        for (int k = 0; k < 64; ++k) acc += xs[n * 64 + k] * Ws[k * 64 + j];
        h[node * 64 + j] = acc;
    }
}

__global__ __launch_bounds__(256) void k_mm_bn(const float* __restrict__ src,
                                               const float* __restrict__ scale,
                                               const float* __restrict__ shift,
                                               const float* __restrict__ W,
                                               float* __restrict__ h) {
    __shared__ float Ws[64 * 64];
    __shared__ float xs[4 * 64];
    int t = threadIdx.x;
    for (int k = t; k < 64 * 64; k += 256) Ws[k] = W[k];
    int n0 = blockIdx.x * 4;
    int j = t & 63, n = t >> 6;
    int node = n0 + n;
    int gidx = n0 * 64 + t;
    float v = (gidx < NN * 64) ? src[gidx] : 0.0f;
    xs[t] = fmaxf(scale[j] * v + shift[j], 0.0f);
    __syncthreads();
    if (node < NN) {
        float acc = 0.f;
        #pragma unroll
        for (int k = 0; k < 64; ++k) acc += xs[n * 64 + k] * Ws[k * 64 + j];
        h[node * 64 + j] = acc;
    }
}

// ---------------- CSR gather aggregation (fused self-loop + bias) ----------------
__global__ __launch_bounds__(256) void k_gather(const int* __restrict__ cursor,
                                                const int* __restrict__ eidx,
                                                const float* __restrict__ dinv,
                                                const float* __restrict__ h,
                                                const float* __restrict__ b,
                                                float* __restrict__ agg) {
    int node = blockIdx.x * 4 + (threadIdx.x >> 6);
    if (node >= NN) return;
    int lane = threadIdx.x & 63;
    int eslot = lane >> 4;
    int fb = (lane & 15) << 2;
    int start = cursor[node];
    int end = (node < NN - 1) ? cursor[node + 1] : NE;
    float4 acc = make_float4(0.f, 0.f, 0.f, 0.f);
    for (int e = start + eslot; e < end; e += 4) {
        int r = eidx[e];
        float dr = dinv[r];
        const float4 hv = *reinterpret_cast<const float4*>(&h[r * 64 + fb]);
        acc.x += hv.x * dr; acc.y += hv.y * dr; acc.z += hv.z * dr; acc.w += hv.w * dr;
    }
    acc.x += __shfl_xor(acc.x, 16); acc.y += __shfl_xor(acc.y, 16);
    acc.z += __shfl_xor(acc.z, 16); acc.w += __shfl_xor(acc.w, 16);
    acc.x += __shfl_xor(acc.x, 32); acc.y += __shfl_xor(acc.y, 32);
    acc.z += __shfl_xor(acc.z, 32); acc.w += __shfl_xor(acc.w, 32);
    if (lane < 16) {
        float dc = dinv[node];
        const float4 hv = *reinterpret_cast<const float4*>(&h[node * 64 + fb]);
        const float4 bv = *reinterpret_cast<const float4*>(&b[fb]);
        float4 o;
        o.x = dc * (acc.x + dc * hv.x) + bv.x;
        o.y = dc * (acc.y + dc * hv.y) + bv.y;
        o.z = dc * (acc.z + dc * hv.z) + bv.z;
        o.w = dc * (acc.w + dc * hv.w) + bv.w;
        *reinterpret_cast<float4*>(&agg[node * 64 + fb]) = o;
    }
}

// ---------------- batchnorm stats ----------------
__global__ __launch_bounds__(256) void k_bn_stats(const float* __restrict__ agg,
                                                  float* __restrict__ bnsum, float* __restrict__ bnsq) {
    __shared__ float ls[256], lq[256];
    int j = threadIdx.x & 63, nl = threadIdx.x >> 6;
    float a = 0.f, b = 0.f;
    for (int i = blockIdx.x * 4 + nl; i < NN; i += gridDim.x * 4) {
        float v = agg[i * 64 + j]; a += v; b += v * v;
    }
    ls[threadIdx.x] = a; lq[threadIdx.x] = b; __syncthreads();
    if (threadIdx.x < 128) { ls[threadIdx.x] += ls[threadIdx.x + 128]; lq[threadIdx.x] += lq[threadIdx.x + 128]; }
    __syncthreads();
    if (threadIdx.x < 64) {
        atomicAdd(&bnsum[j], ls[threadIdx.x] + ls[threadIdx.x + 64]);
        atomicAdd(&bnsq[j],  lq[threadIdx.x] + lq[threadIdx.x + 64]);
    }
}

__global__ void k_bn_finalize(const float* __restrict__ bnsum, const float* __restrict__ bnsq,
                              const float* __restrict__ g, const float* __restrict__ bt,
                              float* __restrict__ scale, float* __restrict__ shift) {
    int j = threadIdx.x;
    if (j < FD) {
        float mean = bnsum[j] * (1.0f / NN);
        float var  = bnsq[j] * (1.0f / NN) - mean * mean;
        float rinv = rsqrtf(var + BN_EPS);
        float sc = g[j] * rinv;
        scale[j] = sc;
        shift[j] = bt[j] - sc * mean;
    }
}

// ---------------- fused BN + pooling (segmented) ----------------
__global__ __launch_bounds__(256) void k_pool_bn(const float* __restrict__ agg,
                                                 const float* __restrict__ scale,
                                                 const float* __restrict__ shift,
                                                 const int* __restrict__ batch,
                                                 float* __restrict__ pooled,
                                                 float* __restrict__ cnt) {
    const int wpb = 4;
    int wave = blockIdx.x * wpb + (threadIdx.x >> 6);
    int lane = threadIdx.x & 63;
    const int nwaves = gridDim.x * wpb;
    int chunk = (NN + nwaves - 1) / nwaves;
    int i0 = wave * chunk;
    int i1 = i0 + chunk; if (i1 > NN) i1 = NN;
    if (i0 >= NN) return;
    float sc = scale[lane], sh = shift[lane];
    float acc = 0.0f;
    int curb = batch[i0];
    int runlen = 0;
    for (int i = i0; i < i1; ++i) {
        int b = batch[i];
        if (b != curb) {
            atomicAdd(&pooled[curb * 64 + lane], acc);
            if (lane == 0) atomicAdd(&cnt[curb], (float)runlen);
            acc = 0.0f; runlen = 0; curb = b;
        }
        acc += fmaxf(sc * agg[i * 64 + lane] + sh, 0.0f);
        ++runlen;
    }
    atomicAdd(&pooled[curb * 64 + lane], acc);
    if (lane == 0) atomicAdd(&cnt[curb], (float)runlen);
}

__global__ __launch_bounds__(128) void k_fc(const float* __restrict__ pooled, const float* __restrict__ cnt,
                                            const float* __restrict__ fw1, const float* __restrict__ fb1,
                                            const float* __restrict__ fw2, const float* __restrict__ fb2,
                                            float* __restrict__ out) {
    __shared__ float p[64], hsh[128];
    int g = blockIdx.x, t = threadIdx.x;
    if (t < 64) {
        float c = cnt[g]; c = c < 1.f ? 1.f : c;
        p[t] = pooled[g * 64 + t] / c;
    }
    __syncthreads();
    float acc = fb1[t];
    #pragma unroll 8
    for (int k = 0; k < 64; ++k) acc += p[k] * fw1[t * 64 + k];
    hsh[t] = fmaxf(acc, 0.f);
    __syncthreads();
    if (t < 10) {
        float o = fb2[t];
        #pragma unroll 8
        for (int k = 0; k < 128; ++k) o += hsh[k] * fw2[t * 128 + k];
        out[g * 10 + t] = o;
    }
}

// ---------------- launch ----------------
extern "C" void kernel_launch(void* const* d_in, const int* in_sizes, int n_in,
                              void* d_out, int out_size, void* d_ws, size_t ws_size,
                              hipStream_t stream) {
    const float* x   = (const float*)d_in[0];
    const int* ei    = (const int*)d_in[1];
    const int* batch = (const int*)d_in[2];
    const float* W[5]  = {nullptr, (const float*)d_in[3],  (const float*)d_in[7],
                                   (const float*)d_in[11], (const float*)d_in[15]};
    const float* bb[5] = {nullptr, (const float*)d_in[4],  (const float*)d_in[8],
                                   (const float*)d_in[12], (const float*)d_in[16]};
    const float* gg[5] = {nullptr, (const float*)d_in[5],  (const float*)d_in[9],
                                   (const float*)d_in[13], (const float*)d_in[17]};
    const float* bt[5] = {nullptr, (const float*)d_in[6],  (const float*)d_in[10],
                                   (const float*)d_in[14], (const float*)d_in[18]};
    const float* fw1 = (const float*)d_in[19];
    const float* fb1 = (const float*)d_in[20];
    const float* fw2 = (const float*)d_in[21];
    const float* fb2 = (const float*)d_in[22];
    float* out = (float*)d_out;

    const int* row = ei;
    const int* col = ei + NE;

    float* ws = (float*)d_ws;
    int*   cursor  = (int*)ws;              // N
    int*   degi    = (int*)(ws + 50000);    // N
    int*   eidx    = (int*)(ws + 100000);   // E
    float* dinv    = ws + 900000;           // N
    float* xd      = ws + 950000;           // N
    int*   bsum    = (int*)(ws + 1000000);  // SCAN_NBLK
    float* s       = ws + 1001000;          // N
    float* stats   = ws + 1051008;
    float* bnsum   = ws + 1051072;
    float* bnsq    = ws + 1051136;
    float* scale   = ws + 1051200;
    float* shift   = ws + 1051264;
    float* pooled  = ws + 1051360;          // 64*64
    float* cnt     = ws + 1055456;          // 64
    int*   gcnt    = (int*)(ws + 1056000);  // NBIN
    float* hbuf    = ws + 1100000;          // N*64 (bins alias this region pre-layer2)
    int*   bins    = (int*)(ws + 1100000);  // NBIN*BINCAP ints = 1.2M <= 3.2M
    float* aggbuf  = ws + 4300000;          // N*64

    const int B = 256;
    int gN  = (NN + B - 1) / B;

    // CSR build (binned) + dinv
    hipMemsetAsync(gcnt, 0, NBIN * sizeof(int), stream);
    k_binscatter<<<SCH_NBLK, B, 0, stream>>>(row, col, gcnt, bins);
    k_bindeg<<<NBIN, B, 0, stream>>>(gcnt, bins, degi);
    k_scan_blk<<<SCAN_NBLK, SCAN_B, 0, stream>>>(degi, cursor, bsum, dinv);
    k_scan_top<<<1, SCAN_B, 0, stream>>>(bsum);
    k_scan_add<<<SCAN_NBLK, SCAN_B, 0, stream>>>(cursor, bsum);
    k_binfill<<<NBIN, B, 0, stream>>>(gcnt, bins, cursor, eidx);

    // layer 1 (scalar propagation + folded BN)
    k_xd<<<gN, B, 0, stream>>>(x, dinv, xd);
    k_l1_gather<<<gN, B, 0, stream>>>(cursor, eidx, xd, x, dinv, s);
    hipMemsetAsync(stats, 0, 2 * sizeof(float), stream);
    k_scalar_stats<<<256, B, 0, stream>>>(s, stats);
    k_l1_coeffs<<<1, 64, 0, stream>>>(stats, W[1], bb[1], gg[1], bt[1], scale, shift);

    // layer 2: fused l1-apply + matmul, gather, stats
    k_mm_l1<<<(NN + 3) / 4, B, 0, stream>>>(s, scale, shift, W[2], hbuf);
    k_gather<<<(NN + 3) / 4, B, 0, stream>>>(cursor, eidx, dinv, hbuf, bb[2], aggbuf);
    hipMemsetAsync(bnsum, 0, 128 * sizeof(float), stream);
    k_bn_stats<<<512, B, 0, stream>>>(aggbuf, bnsum, bnsq);
    k_bn_finalize<<<1, 64, 0, stream>>>(bnsum, bnsq, gg[2], bt[2], scale, shift);

    // layers 3,4: fused bn+matmul, gather, stats
    for (int L = 3; L <= 4; ++L) {
        k_mm_bn<<<(NN + 3) / 4, B, 0, stream>>>(aggbuf, scale, shift, W[L], hbuf);
        k_gather<<<(NN + 3) / 4, B, 0, stream>>>(cursor, eidx, dinv, hbuf, bb[L], aggbuf);
        hipMemsetAsync(bnsum, 0, 128 * sizeof(float), stream);
        k_bn_stats<<<512, B, 0, stream>>>(aggbuf, bnsum, bnsq);
        k_bn_finalize<<<1, 64, 0, stream>>>(bnsum, bnsq, gg[L], bt[L], scale, shift);
    }

    // fused BN + pool (segmented) + FC
    hipMemsetAsync(pooled, 0, (64 * 64 + 64) * sizeof(float), stream);
    k_pool_bn<<<512, B, 0, stream>>>(aggbuf, scale, shift, batch, pooled, cnt);
    k_fc<<<NG, 128, 0, stream>>>(pooled, cnt, fw1, fb1, fw2, fb2, out);
}

// Round 7
// 345.673 us; speedup vs baseline: 3.5093x; 1.0467x over previous
//
#include <hip/hip_runtime.h>

#define NN 50000
#define NE 800000
#define NG 64
#define FD 64
#define BN_EPS 1e-5f
#define SCAN_B 256
#define NBIN 98            // ceil(50000/512)
#define BINCAP 12288
#define SCH 4096
#define SCH_NBLK ((NE + SCH - 1) / SCH)          // 196
#define INV_NN (1.0f / NN)

// ---------------- CSR build: binned two-pass ----------------
__global__ __launch_bounds__(256) void k_binscatter(const int* __restrict__ row,
                                                    const int* __restrict__ col,
                                                    int* __restrict__ gcnt,
                                                    int* __restrict__ bins) {
    __shared__ int stage[SCH];
    __shared__ int cnt[NBIN], off[NBIN + 1], cur[NBIN], gbase[NBIN];
    int t = threadIdx.x;
    int e0 = blockIdx.x * SCH;
    int nk = NE - e0; if (nk > SCH) nk = SCH;
    if (nk <= 0) return;
    for (int b = t; b < NBIN; b += 256) cnt[b] = 0;
    __syncthreads();
    for (int k = t; k < nk; k += 256) {
        int c = col[e0 + k];
        atomicAdd(&cnt[c >> 9], 1);
    }
    __syncthreads();
    if (t == 0) {
        int run = 0;
        for (int b = 0; b < NBIN; ++b) { off[b] = run; run += cnt[b]; }
        off[NBIN] = run;
    }
    __syncthreads();
    if (t < NBIN) {
        cur[t] = off[t];
        gbase[t] = t * BINCAP + atomicAdd(&gcnt[t], cnt[t]);
    }
    __syncthreads();
    for (int k = t; k < nk; k += 256) {
        int c = col[e0 + k];
        int r = row[e0 + k];
        int b = c >> 9;
        int pos = atomicAdd(&cur[b], 1);
        stage[pos] = ((c & 511) << 16) | r;
    }
    __syncthreads();
    for (int k = t; k < nk; k += 256) {
        int lo = 0, hi = NBIN - 1;
        while (lo < hi) {
            int mid = (lo + hi + 1) >> 1;
            if (off[mid] <= k) lo = mid; else hi = mid - 1;
        }
        bins[gbase[lo] + (k - off[lo])] = stage[k];
    }
}

// per-bin degree hist + in-block scan + dinv + xd  (one block per bin of 512 nodes)
__global__ __launch_bounds__(256) void k_binscan(const int* __restrict__ gcnt,
                                                 const int* __restrict__ bins,
                                                 const float* __restrict__ x,
                                                 int* __restrict__ cursor,
                                                 int* __restrict__ bsum,
                                                 float* __restrict__ dinv,
                                                 float* __restrict__ xd) {
    __shared__ int ldeg[512];
    __shared__ int psc[256];
    int b = blockIdx.x, t = threadIdx.x;
    for (int l = t; l < 512; l += 256) ldeg[l] = 0;
    __syncthreads();
    int nb = gcnt[b];
    const int* bp = bins + b * BINCAP;
    for (int k = t; k < nb; k += 256) atomicAdd(&ldeg[bp[k] >> 16], 1);
    __syncthreads();
    int d0 = ldeg[2 * t], d1 = ldeg[2 * t + 1];
    int pv = d0 + d1;
    psc[t] = pv;
    __syncthreads();
    for (int off = 1; off < 256; off <<= 1) {
        int u = (t >= off) ? psc[t - off] : 0;
        __syncthreads();
        psc[t] += u;
        __syncthreads();
    }
    int excl = psc[t] - pv;
    int base = b << 9;
    int i0 = base + 2 * t, i1 = i0 + 1;
    if (i0 < NN) {
        cursor[i0] = excl;
        float dv = rsqrtf((float)d0 + 1.0f);
        dinv[i0] = dv; xd[i0] = x[i0] * dv;
    }
    if (i1 < NN) {
        cursor[i1] = excl + d0;
        float dv = rsqrtf((float)d1 + 1.0f);
        dinv[i1] = dv; xd[i1] = x[i1] * dv;
    }
    if (t == 255) bsum[b] = psc[255];
}

// scan the 98 bin sums -> exclusive bin offsets; also zero stats
__global__ __launch_bounds__(SCAN_B) void k_scan_top(int* __restrict__ bsum,
                                                     float* __restrict__ stats) {
    __shared__ int sh[SCAN_B];
    int t = threadIdx.x;
    if (t < 2) stats[t] = 0.0f;
    int v = (t < NBIN) ? bsum[t] : 0;
    sh[t] = v;
    __syncthreads();
    for (int off = 1; off < SCAN_B; off <<= 1) {
        int u = (t >= off) ? sh[t - off] : 0;
        __syncthreads();
        sh[t] += u;
        __syncthreads();
    }
    if (t < NBIN) bsum[t] = sh[t] - v;
}

// per-bin fill of eidx (contiguous output range per block)
__global__ __launch_bounds__(256) void k_binfill(const int* __restrict__ gcnt,
                                                 const int* __restrict__ bins,
                                                 const int* __restrict__ cursor,
                                                 const int* __restrict__ bsum,
                                                 int* __restrict__ eidx) {
    __shared__ int lcur[512];
    int b = blockIdx.x, t = threadIdx.x;
    int base = b << 9;
    int bofs = bsum[b];
    for (int l = t; l < 512; l += 256) {
        int i = base + l;
        lcur[l] = (i < NN) ? cursor[i] + bofs : 0;
    }
    __syncthreads();
    int nb = gcnt[b];
    const int* bp = bins + b * BINCAP;
    for (int k = t; k < nb; k += 256) {
        int v = bp[k];
        int pos = atomicAdd(&lcur[v >> 16], 1);
        eidx[pos] = v & 0xFFFF;
    }
}

// ---------------- layer 1: scalar propagation + fused stats ----------------
__global__ __launch_bounds__(256) void k_l1_gather(const int* __restrict__ cursor,
                                                   const int* __restrict__ bsum,
                                                   const int* __restrict__ eidx,
                                                   const float* __restrict__ xd,
                                                   const float* __restrict__ x,
                                                   const float* __restrict__ dinv,
                                                   float* __restrict__ s,
                                                   float* __restrict__ stats) {
    __shared__ float ls[256], lq[256];
    int t = threadIdx.x;
    int i = blockIdx.x * 256 + t;
    float sv = 0.0f;
    if (i < NN) {
        int start = cursor[i] + bsum[i >> 9];
        int end = (i < NN - 1) ? cursor[i + 1] + bsum[(i + 1) >> 9] : NE;
        float acc = 0.0f;
        for (int k = start; k < end; ++k) acc += xd[eidx[k]];
        float di = dinv[i];
        sv = di * (acc + di * x[i]);
        s[i] = sv;
    }
    ls[t] = sv; lq[t] = sv * sv;
    __syncthreads();
    for (int st = 128; st > 0; st >>= 1) {
        if (t < st) { ls[t] += ls[t + st]; lq[t] += lq[t + st]; }
        __syncthreads();
    }
    if (t == 0) { atomicAdd(&stats[0], ls[0]); atomicAdd(&stats[1], lq[0]); }
}

// ---------------- fused coeffs + activation + 64x64 matmul ----------------
__global__ __launch_bounds__(256) void k_mm_l1(const float* __restrict__ s,
                                               const float* __restrict__ stats,
                                               const float* __restrict__ W1,
                                               const float* __restrict__ g1,
                                               const float* __restrict__ bt1,
                                               const float* __restrict__ W,
                                               float* __restrict__ h) {
    __shared__ float Ws[64 * 64];
    __shared__ float xs[4 * 64];
    __shared__ float als[64], cls[64];
    int t = threadIdx.x;
    for (int k = t; k < 64 * 64; k += 256) Ws[k] = W[k];
    if (t < 64) {
        float mean = stats[0] * INV_NN;
        float var  = stats[1] * INV_NN - mean * mean;
        float w = W1[t];
        float rinv = rsqrtf(var * w * w + BN_EPS);
        float a = g1[t] * w * rinv;
        als[t] = a;
        cls[t] = bt1[t] - a * mean;
    }
    __syncthreads();
    int n0 = blockIdx.x * 4;
    int j = t & 63, n = t >> 6;
    int node = n0 + n;
    float sv = (node < NN) ? s[node] : 0.0f;
    xs[t] = fmaxf(als[j] * sv + cls[j], 0.0f);
    __syncthreads();
    if (node < NN) {
        float acc = 0.f;
        #pragma unroll
        for (int k = 0; k < 64; ++k) acc += xs[n * 64 + k] * Ws[k * 64 + j];
        h[node * 64 + j] = acc;
    }
}

__global__ __launch_bounds__(256) void k_mm_bn(const float* __restrict__ src,
                                               const float* __restrict__ bnsum,
                                               const float* __restrict__ bnsq,
                                               const float* __restrict__ g,
                                               const float* __restrict__ bt,
                                               const float* __restrict__ W,
                                               float* __restrict__ h) {
    __shared__ float Ws[64 * 64];
    __shared__ float xs[4 * 64];
    __shared__ float scl[64], shf[64];
    int t = threadIdx.x;
    for (int k = t; k < 64 * 64; k += 256) Ws[k] = W[k];
    if (t < 64) {
        float mean = bnsum[t] * INV_NN;
        float var  = bnsq[t] * INV_NN - mean * mean;
        float rinv = rsqrtf(var + BN_EPS);
        float sc = g[t] * rinv;
        scl[t] = sc;
        shf[t] = bt[t] - sc * mean;
    }
    __syncthreads();
    int n0 = blockIdx.x * 4;
    int j = t & 63, n = t >> 6;
    int node = n0 + n;
    int gidx = n0 * 64 + t;
    float v = (gidx < NN * 64) ? src[gidx] : 0.0f;
    xs[t] = fmaxf(scl[j] * v + shf[j], 0.0f);
    __syncthreads();
    if (node < NN) {
        float acc = 0.f;
        #pragma unroll
        for (int k = 0; k < 64; ++k) acc += xs[n * 64 + k] * Ws[k * 64 + j];
        h[node * 64 + j] = acc;
    }
}

// ---------------- CSR gather aggregation (self-loop + bias; zeros bn accumulators) ----------------
__global__ __launch_bounds__(256) void k_gather(const int* __restrict__ cursor,
                                                const int* __restrict__ bsum,
                                                const int* __restrict__ eidx,
                                                const float* __restrict__ dinv,
                                                const float* __restrict__ h,
                                                const float* __restrict__ b,
                                                float* __restrict__ agg,
                                                float* __restrict__ bnsumz,
                                                float* __restrict__ bnsqz) {
    if (blockIdx.x == 0) {
        int t = threadIdx.x;
        if (t < 64) bnsumz[t] = 0.0f;
        else if (t < 128) bnsqz[t - 64] = 0.0f;
    }
    int node = blockIdx.x * 4 + (threadIdx.x >> 6);
    if (node >= NN) return;
    int lane = threadIdx.x & 63;
    int eslot = lane >> 4;
    int fb = (lane & 15) << 2;
    int start = cursor[node] + bsum[node >> 9];
    int end = (node < NN - 1) ? cursor[node + 1] + bsum[(node + 1) >> 9] : NE;
    float4 acc = make_float4(0.f, 0.f, 0.f, 0.f);
    for (int e = start + eslot; e < end; e += 4) {
        int r = eidx[e];
        float dr = dinv[r];
        const float4 hv = *reinterpret_cast<const float4*>(&h[r * 64 + fb]);
        acc.x += hv.x * dr; acc.y += hv.y * dr; acc.z += hv.z * dr; acc.w += hv.w * dr;
    }
    acc.x += __shfl_xor(acc.x, 16); acc.y += __shfl_xor(acc.y, 16);
    acc.z += __shfl_xor(acc.z, 16); acc.w += __shfl_xor(acc.w, 16);
    acc.x += __shfl_xor(acc.x, 32); acc.y += __shfl_xor(acc.y, 32);
    acc.z += __shfl_xor(acc.z, 32); acc.w += __shfl_xor(acc.w, 32);
    if (lane < 16) {
        float dc = dinv[node];
        const float4 hv = *reinterpret_cast<const float4*>(&h[node * 64 + fb]);
        const float4 bv = *reinterpret_cast<const float4*>(&b[fb]);
        float4 o;
        o.x = dc * (acc.x + dc * hv.x) + bv.x;
        o.y = dc * (acc.y + dc * hv.y) + bv.y;
        o.z = dc * (acc.z + dc * hv.z) + bv.z;
        o.w = dc * (acc.w + dc * hv.w) + bv.w;
        *reinterpret_cast<float4*>(&agg[node * 64 + fb]) = o;
    }
}

// ---------------- batchnorm stats (optionally zeros pooled/cnt) ----------------
__global__ __launch_bounds__(256) void k_bn_stats(const float* __restrict__ agg,
                                                  float* __restrict__ bnsum, float* __restrict__ bnsq,
                                                  float* __restrict__ pooledz, float* __restrict__ cntz) {
    if (pooledz != nullptr && blockIdx.x == 0) {
        for (int k = threadIdx.x; k < 64 * 64; k += 256) pooledz[k] = 0.0f;
        if (threadIdx.x < 64) cntz[threadIdx.x] = 0.0f;
    }
    __shared__ float ls[256], lq[256];
    int j = threadIdx.x & 63, nl = threadIdx.x >> 6;
    float a = 0.f, b = 0.f;
    for (int i = blockIdx.x * 4 + nl; i < NN; i += gridDim.x * 4) {
        float v = agg[i * 64 + j]; a += v; b += v * v;
    }
    ls[threadIdx.x] = a; lq[threadIdx.x] = b; __syncthreads();
    if (threadIdx.x < 128) { ls[threadIdx.x] += ls[threadIdx.x + 128]; lq[threadIdx.x] += lq[threadIdx.x + 128]; }
    __syncthreads();
    if (threadIdx.x < 64) {
        atomicAdd(&bnsum[j], ls[threadIdx.x] + ls[threadIdx.x + 64]);
        atomicAdd(&bnsq[j],  lq[threadIdx.x] + lq[threadIdx.x + 64]);
    }
}

// ---------------- fused BN-finalize + BN + pooling (segmented) ----------------
__global__ __launch_bounds__(256) void k_pool_bn(const float* __restrict__ agg,
                                                 const float* __restrict__ bnsum,
                                                 const float* __restrict__ bnsq,
                                                 const float* __restrict__ g4,
                                                 const float* __restrict__ bt4,
                                                 const int* __restrict__ batch,
                                                 float* __restrict__ pooled,
                                                 float* __restrict__ cnt) {
    const int wpb = 4;
    int wave = blockIdx.x * wpb + (threadIdx.x >> 6);
    int lane = threadIdx.x & 63;
    const int nwaves = gridDim.x * wpb;
    int chunk = (NN + nwaves - 1) / nwaves;
    int i0 = wave * chunk;
    int i1 = i0 + chunk; if (i1 > NN) i1 = NN;
    if (i0 >= NN) return;
    float mean = bnsum[lane] * INV_NN;
    float var  = bnsq[lane] * INV_NN - mean * mean;
    float rinv = rsqrtf(var + BN_EPS);
    float sc = g4[lane] * rinv;
    float sh = bt4[lane] - sc * mean;
    float acc = 0.0f;
    int curb = batch[i0];
    int runlen = 0;
    for (int i = i0; i < i1; ++i) {
        int b = batch[i];
        if (b != curb) {
            atomicAdd(&pooled[curb * 64 + lane], acc);
            if (lane == 0) atomicAdd(&cnt[curb], (float)runlen);
            acc = 0.0f; runlen = 0; curb = b;
        }
        acc += fmaxf(sc * agg[i * 64 + lane] + sh, 0.0f);
        ++runlen;
    }
    atomicAdd(&pooled[curb * 64 + lane], acc);
    if (lane == 0) atomicAdd(&cnt[curb], (float)runlen);
}

__global__ __launch_bounds__(128) void k_fc(const float* __restrict__ pooled, const float* __restrict__ cnt,
                                            const float* __restrict__ fw1, const float* __restrict__ fb1,
                                            const float* __restrict__ fw2, const float* __restrict__ fb2,
                                            float* __restrict__ out) {
    __shared__ float p[64], hsh[128];
    int g = blockIdx.x, t = threadIdx.x;
    if (t < 64) {
        float c = cnt[g]; c = c < 1.f ? 1.f : c;
        p[t] = pooled[g * 64 + t] / c;
    }
    __syncthreads();
    float acc = fb1[t];
    #pragma unroll 8
    for (int k = 0; k < 64; ++k) acc += p[k] * fw1[t * 64 + k];
    hsh[t] = fmaxf(acc, 0.f);
    __syncthreads();
    if (t < 10) {
        float o = fb2[t];
        #pragma unroll 8
        for (int k = 0; k < 128; ++k) o += hsh[k] * fw2[t * 128 + k];
        out[g * 10 + t] = o;
    }
}

// ---------------- launch ----------------
extern "C" void kernel_launch(void* const* d_in, const int* in_sizes, int n_in,
                              void* d_out, int out_size, void* d_ws, size_t ws_size,
                              hipStream_t stream) {
    const float* x   = (const float*)d_in[0];
    const int* ei    = (const int*)d_in[1];
    const int* batch = (const int*)d_in[2];
    const float* W[5]  = {nullptr, (const float*)d_in[3],  (const float*)d_in[7],
                                   (const float*)d_in[11], (const float*)d_in[15]};
    const float* bb[5] = {nullptr, (const float*)d_in[4],  (const float*)d_in[8],
                                   (const float*)d_in[12], (const float*)d_in[16]};
    const float* gg[5] = {nullptr, (const float*)d_in[5],  (const float*)d_in[9],
                                   (const float*)d_in[13], (const float*)d_in[17]};
    const float* bt[5] = {nullptr, (const float*)d_in[6],  (const float*)d_in[10],
                                   (const float*)d_in[14], (const float*)d_in[18]};
    const float* fw1 = (const float*)d_in[19];
    const float* fb1 = (const float*)d_in[20];
    const float* fw2 = (const float*)d_in[21];
    const float* fb2 = (const float*)d_in[22];
    float* out = (float*)d_out;

    const int* row = ei;
    const int* col = ei + NE;

    float* ws = (float*)d_ws;
    int*   cursor  = (int*)ws;              // N
    int*   eidx    = (int*)(ws + 50000);    // E
    float* dinv    = ws + 850000;           // N
    float* xd      = ws + 900000;           // N
    int*   bsum    = (int*)(ws + 950000);   // NBIN
    float* s       = ws + 951000;           // N
    float* stats   = ws + 1001008;
    float* bnsum   = ws + 1001072;
    float* bnsq    = ws + 1001136;
    float* pooled  = ws + 1001360;          // 64*64
    float* cnt     = ws + 1005456;          // 64
    int*   gcnt    = (int*)(ws + 1056000);  // NBIN
    float* hbuf    = ws + 1100000;          // N*64 (bins alias this region pre-layer2)
    int*   bins    = (int*)(ws + 1100000);  // NBIN*BINCAP ints
    float* aggbuf  = ws + 4300000;          // N*64

    const int B = 256;
    int gN = (NN + B - 1) / B;

    // CSR build (binned) + dinv + xd
    hipMemsetAsync(gcnt, 0, NBIN * sizeof(int), stream);
    k_binscatter<<<SCH_NBLK, B, 0, stream>>>(row, col, gcnt, bins);
    k_binscan<<<NBIN, B, 0, stream>>>(gcnt, bins, x, cursor, bsum, dinv, xd);
    k_scan_top<<<1, SCAN_B, 0, stream>>>(bsum, stats);
    k_binfill<<<NBIN, B, 0, stream>>>(gcnt, bins, cursor, bsum, eidx);

    // layer 1: scalar propagation + fused stats
    k_l1_gather<<<gN, B, 0, stream>>>(cursor, bsum, eidx, xd, x, dinv, s, stats);

    // layer 2: fused coeffs+l1-apply+matmul, gather (zeros bn accum), stats
    k_mm_l1<<<(NN + 3) / 4, B, 0, stream>>>(s, stats, W[1], gg[1], bt[1], W[2], hbuf);
    k_gather<<<(NN + 3) / 4, B, 0, stream>>>(cursor, bsum, eidx, dinv, hbuf, bb[2], aggbuf, bnsum, bnsq);
    k_bn_stats<<<512, B, 0, stream>>>(aggbuf, bnsum, bnsq, nullptr, nullptr);

    // layers 3,4
    for (int L = 3; L <= 4; ++L) {
        k_mm_bn<<<(NN + 3) / 4, B, 0, stream>>>(aggbuf, bnsum, bnsq, gg[L - 1], bt[L - 1], W[L], hbuf);
        k_gather<<<(NN + 3) / 4, B, 0, stream>>>(cursor, bsum, eidx, dinv, hbuf, bb[L], aggbuf, bnsum, bnsq);
        k_bn_stats<<<512, B, 0, stream>>>(aggbuf, bnsum, bnsq,
                                          (L == 4) ? pooled : nullptr, (L == 4) ? cnt : nullptr);
    }

    // fused finalize+BN+pool (segmented) + FC
    k_pool_bn<<<512, B, 0, stream>>>(aggbuf, bnsum, bnsq, gg[4], bt[4], batch, pooled, cnt);
    k_fc<<<NG, 128, 0, stream>>>(pooled, cnt, fw1, fb1, fw2, fb2, out);
}